// Round 8
// baseline (630.565 us; speedup 1.0000x reference)
//
#include <hip/hip_runtime.h>
#include <stdint.h>

#define B_ 8
#define T_ 2048
#define C_ 1024
#define E_ 8
#define K_ 2
#define CAP_ 320
#define DFF_ 4096
#define S_ (T_*K_)          // 4096 assignments per batch row
#define NTOK (B_*T_)        // 16384 tokens
#define ROWS_PER_E (B_*CAP_) // 2560

typedef __attribute__((ext_vector_type(8))) short short8;
typedef __attribute__((ext_vector_type(4))) float floatx4;

__device__ __forceinline__ unsigned short f2bf(float f) {
  union { float f; unsigned u; } v; v.f = f;
  unsigned r = v.u + 0x7fffu + ((v.u >> 16) & 1u);
  return (unsigned short)(r >> 16);
}
__device__ __forceinline__ float bf2f(unsigned short h) {
  union { unsigned u; float f; } v; v.u = ((unsigned)h) << 16;
  return v.f;
}

// async global->LDS, 16B per lane; LDS dest is wave-uniform base + lane*16
#define GLOAD16(g, l) __builtin_amdgcn_global_load_lds( \
    (const __attribute__((address_space(1))) void*)(g), \
    (__attribute__((address_space(3))) void*)(l), 16, 0, 0)

// ---------------- Router: fp64 logits, softmax, top-2 ----------------
__global__ void router_kernel(const float* __restrict__ x, const float* __restrict__ Wg,
                              const float* __restrict__ bg,
                              int* __restrict__ topk_e, float* __restrict__ topk_p)
{
  int token = (int)((blockIdx.x * blockDim.x + threadIdx.x) >> 6);
  int lane = threadIdx.x & 63;
  if (token >= NTOK) return;
  const float* xr = x + (size_t)token * C_;
  double acc[E_];
  #pragma unroll
  for (int e = 0; e < E_; ++e) acc[e] = 0.0;
  for (int c = lane; c < C_; c += 64) {
    double xv = (double)xr[c];
    const float4* w4 = (const float4*)(Wg + (size_t)c * E_);
    float4 wa = w4[0], wb = w4[1];
    acc[0] += xv * (double)wa.x; acc[1] += xv * (double)wa.y;
    acc[2] += xv * (double)wa.z; acc[3] += xv * (double)wa.w;
    acc[4] += xv * (double)wb.x; acc[5] += xv * (double)wb.y;
    acc[6] += xv * (double)wb.z; acc[7] += xv * (double)wb.w;
  }
  #pragma unroll
  for (int off = 32; off; off >>= 1) {
    #pragma unroll
    for (int e = 0; e < E_; ++e) acc[e] += __shfl_down(acc[e], off, 64);
  }
  if (lane == 0) {
    double lg[E_];
    double mx = -1e300;
    #pragma unroll
    for (int e = 0; e < E_; ++e) { lg[e] = acc[e] + (double)bg[e]; mx = fmax(mx, lg[e]); }
    double se = 0.0, pr[E_];
    #pragma unroll
    for (int e = 0; e < E_; ++e) { pr[e] = exp(lg[e] - mx); se += pr[e]; }
    #pragma unroll
    for (int e = 0; e < E_; ++e) pr[e] /= se;
    int e0 = 0;
    #pragma unroll
    for (int e = 1; e < E_; ++e) if (pr[e] > pr[e0]) e0 = e;
    int e1 = -1;
    #pragma unroll
    for (int e = 0; e < E_; ++e) {
      if (e == e0) continue;
      if (e1 < 0 || pr[e] > pr[e1]) e1 = e;
    }
    topk_e[token*2+0] = e0; topk_p[token*2+0] = (float)pr[e0];
    topk_e[token*2+1] = e1; topk_p[token*2+1] = (float)pr[e1];
  }
}

// ---------------- Scan: per-(b,e) positions, capacity, slot map ----------------
__global__ void scan_kernel(const int* __restrict__ topk_e,
                            int* __restrict__ pos_arr,   // [B_*S_], -1 if dropped
                            int* __restrict__ slot_src,  // [E_*B_*CAP_] -> src token t
                            int* __restrict__ counts)    // [E_*B_]
{
  const int b = blockIdx.x;
  const int tid = threadIdx.x;
  const int PT = S_ / 256; // 16
  __shared__ int cnt[256][E_];
  int e_loc[16];
  int local[E_];
  #pragma unroll
  for (int e = 0; e < E_; ++e) local[e] = 0;
  const int* te = topk_e + (size_t)b * S_;
  for (int j = 0; j < PT; ++j) {
    int e = te[tid*PT + j];
    e_loc[j] = e;
    local[e]++;
  }
  #pragma unroll
  for (int e = 0; e < E_; ++e) cnt[tid][e] = local[e];
  __syncthreads();
  if (tid < E_) {
    int run = 0;
    for (int i = 0; i < 256; ++i) { int v = cnt[i][tid]; cnt[i][tid] = run; run += v; }
    counts[tid*B_ + b] = run;   // counts[e][b]
  }
  __syncthreads();
  int base[E_];
  #pragma unroll
  for (int e = 0; e < E_; ++e) base[e] = cnt[tid][e];
  for (int j = 0; j < PT; ++j) {
    int e = e_loc[j];
    int p = base[e]++;
    int s = tid*PT + j;
    if (p < CAP_) {
      pos_arr[(size_t)b*S_ + s] = p;
      slot_src[((size_t)e*B_ + b)*CAP_ + p] = s >> 1;  // token t
    } else {
      pos_arr[(size_t)b*S_ + s] = -1;
    }
  }
}

// ---------------- Transpose + fp32->bf16: in [R][Cc] -> out [Cc][R], per expert ----------------
// 64(r) x 32(c) tiles; writes full 128B out-rows (ushort8 per thread).
__global__ void transpose_conv_kernel(const float* __restrict__ in, unsigned short* __restrict__ out,
                                      int R, int Cc)
{
  __shared__ float tile[64][33];
  const int e = blockIdx.z;
  const float* ine = in + (size_t)e * R * Cc;
  unsigned short* oute = out + (size_t)e * R * Cc;
  const int c0 = blockIdx.x * 32, r0 = blockIdx.y * 64;
  const int tx = threadIdx.x & 7, ty = threadIdx.x >> 3;  // 8 x 32
  #pragma unroll
  for (int p = 0; p < 2; ++p) {
    const int rr = p*32 + ty;
    float4 v = *(const float4*)(ine + (size_t)(r0 + rr) * Cc + c0 + tx*4);
    tile[rr][tx*4+0] = v.x; tile[rr][tx*4+1] = v.y;
    tile[rr][tx*4+2] = v.z; tile[rr][tx*4+3] = v.w;
  }
  __syncthreads();
  // out-row = column c0+ty (32 of them), 64 shorts each; tx picks 8-short segment
  short8 s;
  #pragma unroll
  for (int j = 0; j < 8; ++j) s[j] = (short)f2bf(tile[tx*8+j][ty]);
  *(short8*)(oute + (size_t)(c0 + ty) * R + r0 + tx*8) = s;
}

// ---------------- Dispatch: gather x rows into [nexp][B*CAP][C] bf16 ----------------
__global__ void dispatch_kernel(const float* __restrict__ x, const int* __restrict__ slot_src,
                                const int* __restrict__ counts, unsigned short* __restrict__ Xd,
                                int e_base, int nexp)
{
  int row = (int)((blockIdx.x * blockDim.x + threadIdx.x) >> 6);
  int lane = threadIdx.x & 63;
  int total = nexp * B_ * CAP_;
  if (row >= total) return;
  int el = row / (B_*CAP_);
  int rem = row - el*(B_*CAP_);
  int b = rem / CAP_, slot = rem - b*CAP_;
  int eg = e_base + el;
  int cnt = counts[eg*B_ + b]; if (cnt > CAP_) cnt = CAP_;
  unsigned short* orow = Xd + (size_t)row * C_;
  if (slot < cnt) {
    int t = slot_src[((size_t)eg*B_ + b)*CAP_ + slot];
    const float4* xr = (const float4*)(x + ((size_t)b*T_ + t)*C_);
    #pragma unroll
    for (int i = 0; i < C_/256; ++i) {
      float4 v = xr[i*64 + lane];
      ushort4 o;
      o.x = f2bf(v.x); o.y = f2bf(v.y); o.z = f2bf(v.z); o.w = f2bf(v.w);
      ((ushort4*)orow)[i*64 + lane] = o;
    }
  } else {
    ushort4 z; z.x = z.y = z.z = z.w = 0;
    #pragma unroll
    for (int i = 0; i < C_/256; ++i) ((ushort4*)orow)[i*64 + lane] = z;
  }
}

// ---------------- GEMM 128x128, BK=32, ring-3 LDS, 3 blocks/CU, counted vmcnt ----------------
// A [e][M][Kfull] bf16 x BT [e][N][Kfull] bf16 (+bias if non-null, opt relu) -> Out [e][M][N] bf16
// 256 threads = 4 waves (2x2), per-wave 64x64 output (4x4 16x16 frags). Ring of 3
// K-tile slots (16KB each: A 8KB + B 8KB) = 48KB LDS -> 3 blocks/CU = 12 waves/CU;
// cross-block overlap (m114) covers barrier/vmcnt stalls. Prefetch 2 tiles ahead;
// 4 loads/thread/tile; boundary vmcnt(4) (never 0 until tail). Inner loop is
// compiler-scheduled (fine-grained lgkmcnt, m97 pattern); one lgkmcnt(0) drain at
// the boundary restores the WAR proof for re-staging slot (t+2)%3 == (t-1)%3.
// T2 swizzle (proven 0-conflict for the 16-row fragment groups): k-shorts ^=
// ((row>>1)&3)<<3 on BOTH the global staging source and ds_read offsets (LDS dest
// linear; rule #21).
// Split-K: grid = nsplit * tilesPerSplit; split sp covers K [sp*klen, (sp+1)*klen).
template<int RELU>
__global__ __launch_bounds__(256, 3) void gemm128_kernel(
    const unsigned short* __restrict__ A,
    const unsigned short* __restrict__ BT,
    const float* __restrict__ bias,      // [e][N] or nullptr
    unsigned short* __restrict__ Out0,
    unsigned short* __restrict__ Out1,
    int M, int N, int Kfull, int klen, int tilesPerSplit, int nwg)
{
  __shared__ __align__(16) unsigned short lds[3*8192]; // 48KB: 3 slots x (A 4096 + B 4096 shorts)
  const int NT = N >> 7, MT = M >> 7;
  const int bid = blockIdx.x;
  // bijective XCD swizzle (nwg % 8 == 0 for all launch configs here)
  const int wg = (bid & 7) * (nwg >> 3) + (bid >> 3);
  const int sp  = wg / tilesPerSplit;
  const int wgr = wg - sp * tilesPerSplit;
  const int e  = wgr / (MT*NT);
  const int r2 = wgr - e*(MT*NT);
  const int mt = r2 / NT, nt = r2 - mt*NT;
  const int k0 = sp * klen;
  const unsigned short* Ae = A + (size_t)e * M * Kfull;
  const unsigned short* Be = BT + (size_t)e * N * Kfull;
  const float* be = bias ? (bias + (size_t)e * N) : nullptr;
  unsigned short* Oe = (sp == 0 ? Out0 : Out1) + (size_t)e * M * N;
  const int m0 = mt*128, n0 = nt*128;

  const int tid = threadIdx.x, lane = tid & 63, w = tid >> 6;
  const int wr = w >> 1, wc = w & 1;   // 2 x 2 waves

  floatx4 acc[4][4];
  #pragma unroll
  for (int i = 0; i < 4; ++i)
    #pragma unroll
    for (int j = 0; j < 4; ++j) acc[i][j] = (floatx4){0.f, 0.f, 0.f, 0.f};

  // staging decode. A-tile 128x32 bf16 = 512 chunks of 16B; thread covers chunks
  // tid and 256+tid; same for B. chunk c -> row c>>2, k-slot (c&3)*8 shorts;
  // pre-swizzled global source: src k-off = kslot ^ ((row>>1)&3)<<3 (shorts).
  const int c0 = tid, c1 = 256 + tid;
  const int sr0 = c0 >> 2, sr1 = c1 >> 2;
  const int sq0 = ((c0 & 3)*8) ^ (((sr0 >> 1) & 3) << 3);
  const int sq1 = ((c1 & 3)*8) ^ (((sr1 >> 1) & 3) << 3);
  const unsigned short* gA0 = Ae + (size_t)(m0 + sr0)*Kfull + k0 + sq0;
  const unsigned short* gA1 = Ae + (size_t)(m0 + sr1)*Kfull + k0 + sq1;
  const unsigned short* gB0 = Be + (size_t)(n0 + sr0)*Kfull + k0 + sq0;
  const unsigned short* gB1 = Be + (size_t)(n0 + sr1)*Kfull + k0 + sq1;
  // wave-uniform LDS bases (shorts): A call q at q*2048 + w*512; B region at +4096
  const int la0 = w*512, la1 = 2048 + w*512;
  const int lb0 = 4096 + w*512, lb1 = 4096 + 2048 + w*512;

  // fragment read bases (per lane), same XOR on the k-offset. swz touches row
  // bits 1-2 only; mf*16 / nf*16 row steps don't, so the mf*512 strides hold.
  const int fr = lane & 15, kq = lane >> 4;
  const int aRow = wr*64 + fr;
  const int bRow = wc*64 + fr;
  const int aOff = aRow*32 + ((kq*8) ^ (((aRow >> 1) & 3) << 3));
  const int bOff = 4096 + bRow*32 + ((kq*8) ^ (((bRow >> 1) & 3) << 3));

  const int nk = klen >> 5;

#define STAGE(t, slot) do { \
    GLOAD16(gA0 + (size_t)(t)*32, lds + (slot)*8192 + la0); \
    GLOAD16(gA1 + (size_t)(t)*32, lds + (slot)*8192 + la1); \
    GLOAD16(gB0 + (size_t)(t)*32, lds + (slot)*8192 + lb0); \
    GLOAD16(gB1 + (size_t)(t)*32, lds + (slot)*8192 + lb1); } while(0)

  // prologue: stage tiles 0,1 into slots 0,1 (8 loads/thread)
  STAGE(0, 0); STAGE(1, 1);
  asm volatile("s_waitcnt vmcnt(4)" ::: "memory");   // tile 0 landed
  __builtin_amdgcn_s_barrier();

  for (int t = 0; t < nk; ++t) {
    const int slot = t % 3;
    const int ps   = (t + 2) % 3;
    const unsigned short* sT = lds + slot*8192;

    // fragment reads: compiler schedules these against the MFMAs below,
    // inserting fine-grained lgkmcnt itself (m97 pattern)
    short8 af[4], bf[4];
    #pragma unroll
    for (int mf = 0; mf < 4; ++mf) af[mf] = *(const short8*)(sT + aOff + mf*512);
    #pragma unroll
    for (int nf = 0; nf < 4; ++nf) bf[nf] = *(const short8*)(sT + bOff + nf*512);
    if (t + 2 < nk) STAGE(t+2, ps);

    #pragma unroll
    for (int mf = 0; mf < 4; ++mf)
      #pragma unroll
      for (int nf = 0; nf < 4; ++nf)
        acc[mf][nf] = __builtin_amdgcn_mfma_f32_16x16x32_bf16(af[mf], bf[nf], acc[mf][nf], 0, 0, 0);

    // tile boundary: drain own ds_reads (WAR proof), publish tile t+1
    if (t + 1 < nk) {
      asm volatile("s_waitcnt lgkmcnt(0)" ::: "memory");
      if (t + 2 < nk) asm volatile("s_waitcnt vmcnt(4)" ::: "memory");
      else            asm volatile("s_waitcnt vmcnt(0)" ::: "memory");
      __builtin_amdgcn_s_barrier();
    }
  }
#undef STAGE

  // epilogue: C/D layout col = lane&15, row = (lane>>4)*4 + reg
  const int col = lane & 15, rbase = (lane >> 4) * 4;
  #pragma unroll
  for (int mf = 0; mf < 4; ++mf) {
    const int gr0 = m0 + wr*64 + mf*16 + rbase;
    #pragma unroll
    for (int nf = 0; nf < 4; ++nf) {
      const int gc = n0 + wc*64 + nf*16 + col;
      const float bv = be ? be[gc] : 0.f;
      #pragma unroll
      for (int r = 0; r < 4; ++r) {
        float v = acc[mf][nf][r] + bv;
        if (RELU) v = fmaxf(v, 0.f);
        Oe[(size_t)(gr0 + r)*N + gc] = f2bf(v);
      }
    }
  }
}

// ---------------- Combine: out[b,t] = sum_k p_k * (Y0 + Y1 + b2)[e_k, b, pos_k] ----------------
__global__ void combine_kernel(const unsigned short* __restrict__ Y0, // [E][B*CAP][C] bf16
                               const unsigned short* __restrict__ Y1, // split-1 partial or null
                               const float* __restrict__ b2c,         // [E][C] or null
                               const int* __restrict__ topk_e, const float* __restrict__ topk_p,
                               const int* __restrict__ pos_arr, float* __restrict__ out)
{
  int token = (int)((blockIdx.x * blockDim.x + threadIdx.x) >> 6);
  int lane = threadIdx.x & 63;
  if (token >= NTOK) return;
  int b = token / T_, t = token - b*T_;
  int s0 = b*S_ + t*2;
  float acc[16];
  #pragma unroll
  for (int i = 0; i < 16; ++i) acc[i] = 0.f;
  #pragma unroll
  for (int k = 0; k < 2; ++k) {
    int pos = pos_arr[s0 + k];
    if (pos < 0) continue;
    int e = topk_e[s0 + k];
    float p = topk_p[s0 + k];
    size_t rowoff = (((size_t)e*B_ + b)*CAP_ + pos) * C_;
    const unsigned short* yr0 = Y0 + rowoff;
    const unsigned short* yr1 = Y1 ? (Y1 + rowoff) : nullptr;
    const float* bb = b2c ? (b2c + (size_t)e * C_) : nullptr;
    #pragma unroll
    for (int i = 0; i < 4; ++i) {
      ushort4 v = ((const ushort4*)yr0)[i*64 + lane];
      float s0v = bf2f(v.x), s1v = bf2f(v.y), s2v = bf2f(v.z), s3v = bf2f(v.w);
      if (yr1) {
        ushort4 u = ((const ushort4*)yr1)[i*64 + lane];
        s0v += bf2f(u.x); s1v += bf2f(u.y); s2v += bf2f(u.z); s3v += bf2f(u.w);
      }
      if (bb) {
        float4 bv = ((const float4*)bb)[i*64 + lane];
        s0v += bv.x; s1v += bv.y; s2v += bv.z; s3v += bv.w;
      }
      acc[i*4+0] += p * s0v;
      acc[i*4+1] += p * s1v;
      acc[i*4+2] += p * s2v;
      acc[i*4+3] += p * s3v;
    }
  }
  float4* orow = (float4*)(out + (size_t)token * C_);
  #pragma unroll
  for (int i = 0; i < 4; ++i) {
    float4 o;
    o.x = acc[i*4+0]; o.y = acc[i*4+1]; o.z = acc[i*4+2]; o.w = acc[i*4+3];
    orow[i*64 + lane] = o;
  }
}

extern "C" void kernel_launch(void* const* d_in, const int* in_sizes, int n_in,
                              void* d_out, int out_size, void* d_ws, size_t ws_size,
                              hipStream_t stream)
{
  const float* x  = (const float*)d_in[0];
  const float* Wg = (const float*)d_in[1];
  const float* bg = (const float*)d_in[2];
  const float* W1 = (const float*)d_in[3];
  const float* b1 = (const float*)d_in[4];
  const float* W2 = (const float*)d_in[5];
  const float* b2 = (const float*)d_in[6];
  float* out = (float*)d_out;

  char* ws = (char*)d_ws;
  size_t off = 0;
  auto alloc = [&](size_t bytes) -> char* {
    char* p = ws + off;
    off = (off + bytes + 255) & ~(size_t)255;
    return p;
  };
  int*   topk_e  = (int*)  alloc((size_t)NTOK * K_ * 4);
  float* topk_p  = (float*)alloc((size_t)NTOK * K_ * 4);
  int*   pos_arr = (int*)  alloc((size_t)B_ * S_ * 4);
  int*   slot_src= (int*)  alloc((size_t)E_ * B_ * CAP_ * 4);
  int*   counts  = (int*)  alloc((size_t)E_ * B_ * 4);
  unsigned short* Ybuf = (unsigned short*)alloc((size_t)E_ * ROWS_PER_E * C_ * 2);
  size_t fixed = off;
  const size_t perE = (size_t)C_ * DFF_ * 2      // W^T
                    + (size_t)ROWS_PER_E * C_ * 2  // Xdisp
                    + (size_t)ROWS_PER_E * DFF_ * 2 // H
                    + 3 * 256;
  int k = 8;
  while (k > 1 && fixed + (size_t)k * perE > ws_size) k >>= 1;
  unsigned short* Wt = (unsigned short*)alloc((size_t)k * C_ * DFF_ * 2);
  unsigned short* Xd = (unsigned short*)alloc((size_t)k * ROWS_PER_E * C_ * 2);
  unsigned short* Hb = (unsigned short*)alloc((size_t)k * ROWS_PER_E * DFF_ * 2);

  router_kernel<<<NTOK/4, 256, 0, stream>>>(x, Wg, bg, topk_e, topk_p);
  scan_kernel<<<B_, 256, 0, stream>>>(topk_e, pos_arr, slot_src, counts);

  const bool splitK2 = (k == 8);  // split-1 output reuses Xd (exactly Y-sized at k=8)

  for (int eb = 0; eb < E_; eb += k) {
    // W1 [C][DFF] -> Wt [DFF][C] bf16
    transpose_conv_kernel<<<dim3(DFF_/32, C_/64, k), 256, 0, stream>>>(
        W1 + (size_t)eb * C_ * DFF_, Wt, C_, DFF_);
    dispatch_kernel<<<(k * ROWS_PER_E) / 4, 256, 0, stream>>>(x, slot_src, counts, Xd, eb, k);
    // H = relu(Xd @ W1 + b1)
    {
      int tiles = k * (ROWS_PER_E/128) * (DFF_/128);
      gemm128_kernel<1><<<tiles, 256, 0, stream>>>(
          Xd, Wt, b1 + (size_t)eb * DFF_, Hb, Hb, ROWS_PER_E, DFF_, C_, C_, tiles, tiles);
    }
    // W2 [DFF][C] -> Wt [C][DFF] bf16 (reuses Wt; stream-ordered after GEMM1)
    transpose_conv_kernel<<<dim3(C_/32, DFF_/64, k), 256, 0, stream>>>(
        W2 + (size_t)eb * DFF_ * C_, Wt, DFF_, C_);
    // Y = H @ W2 (+ b2 here only if not split; in split mode combine adds b2)
    {
      int tiles = k * (ROWS_PER_E/128) * (C_/128);
      if (splitK2) {
        gemm128_kernel<0><<<2*tiles, 256, 0, stream>>>(
            Hb, Wt, nullptr, Ybuf, Xd, ROWS_PER_E, C_, DFF_, DFF_/2, tiles, 2*tiles);
      } else {
        gemm128_kernel<0><<<tiles, 256, 0, stream>>>(
            Hb, Wt, b2 + (size_t)eb * C_, Ybuf + (size_t)eb * ROWS_PER_E * C_,
            Ybuf + (size_t)eb * ROWS_PER_E * C_, ROWS_PER_E, C_, DFF_, DFF_, tiles, tiles);
      }
    }
  }

  combine_kernel<<<NTOK/4, 256, 0, stream>>>(
      Ybuf, splitK2 ? Xd : nullptr, splitK2 ? b2 : nullptr,
      topk_e, topk_p, pos_arr, out);
}

// Round 9
// 595.911 us; speedup vs baseline: 1.0582x; 1.0582x over previous
//
#include <hip/hip_runtime.h>
#include <stdint.h>

#define B_ 8
#define T_ 2048
#define C_ 1024
#define E_ 8
#define K_ 2
#define CAP_ 320
#define DFF_ 4096
#define S_ (T_*K_)
#define NTOK (B_*T_)
#define ROWS_PER_E (B_*CAP_) // 2560

typedef __attribute__((ext_vector_type(8))) short short8;
typedef __attribute__((ext_vector_type(4))) float floatx4;

__device__ __forceinline__ unsigned short f2bf(float f) {
  union { float f; unsigned u; } v; v.f = f;
  unsigned r = v.u + 0x7fffu + ((v.u >> 16) & 1u);
  return (unsigned short)(r >> 16);
}
__device__ __forceinline__ float bf2f(unsigned short h) {
  union { unsigned u; float f; } v; v.u = ((unsigned)h) << 16;
  return v.f;
}

#define GLOAD16(g, l) __builtin_amdgcn_global_load_lds( \
    (const __attribute__((address_space(1))) void*)(g), \
    (__attribute__((address_space(3))) void*)(l), 16, 0, 0)

#define BARRIER() asm volatile("s_barrier" ::: "memory")

// ---------------- Router: fp64 logits, softmax, top-2 ----------------
__global__ void router_kernel(const float* __restrict__ x, const float* __restrict__ Wg,
                              const float* __restrict__ bg,
                              int* __restrict__ topk_e, float* __restrict__ topk_p)
{
  int token = (int)((blockIdx.x * blockDim.x + threadIdx.x) >> 6);
  int lane = threadIdx.x & 63;
  if (token >= NTOK) return;
  const float* xr = x + (size_t)token * C_;
  double acc[E_];
  #pragma unroll
  for (int e = 0; e < E_; ++e) acc[e] = 0.0;
  for (int c = lane; c < C_; c += 64) {
    double xv = (double)xr[c];
    const float4* w4 = (const float4*)(Wg + (size_t)c * E_);
    float4 wa = w4[0], wb = w4[1];
    acc[0] += xv * (double)wa.x; acc[1] += xv * (double)wa.y;
    acc[2] += xv * (double)wa.z; acc[3] += xv * (double)wa.w;
    acc[4] += xv * (double)wb.x; acc[5] += xv * (double)wb.y;
    acc[6] += xv * (double)wb.z; acc[7] += xv * (double)wb.w;
  }
  #pragma unroll
  for (int off = 32; off; off >>= 1) {
    #pragma unroll
    for (int e = 0; e < E_; ++e) acc[e] += __shfl_down(acc[e], off, 64);
  }
  if (lane == 0) {
    double lg[E_];
    double mx = -1e300;
    #pragma unroll
    for (int e = 0; e < E_; ++e) { lg[e] = acc[e] + (double)bg[e]; mx = fmax(mx, lg[e]); }
    double se = 0.0, pr[E_];
    #pragma unroll
    for (int e = 0; e < E_; ++e) { pr[e] = exp(lg[e] - mx); se += pr[e]; }
    #pragma unroll
    for (int e = 0; e < E_; ++e) pr[e] /= se;
    int e0 = 0;
    #pragma unroll
    for (int e = 1; e < E_; ++e) if (pr[e] > pr[e0]) e0 = e;
    int e1 = -1;
    #pragma unroll
    for (int e = 0; e < E_; ++e) {
      if (e == e0) continue;
      if (e1 < 0 || pr[e] > pr[e1]) e1 = e;
    }
    topk_e[token*2+0] = e0; topk_p[token*2+0] = (float)pr[e0];
    topk_e[token*2+1] = e1; topk_p[token*2+1] = (float)pr[e1];
  }
}

// ---------------- Scan ----------------
__global__ void scan_kernel(const int* __restrict__ topk_e,
                            int* __restrict__ pos_arr, int* __restrict__ slot_src,
                            int* __restrict__ counts)
{
  const int b = blockIdx.x;
  const int tid = threadIdx.x;
  const int PT = S_ / 256; // 16
  __shared__ int cnt[256][E_];
  int e_loc[16];
  int local[E_];
  #pragma unroll
  for (int e = 0; e < E_; ++e) local[e] = 0;
  const int* te = topk_e + (size_t)b * S_;
  for (int j = 0; j < PT; ++j) {
    int e = te[tid*PT + j];
    e_loc[j] = e;
    local[e]++;
  }
  #pragma unroll
  for (int e = 0; e < E_; ++e) cnt[tid][e] = local[e];
  __syncthreads();
  if (tid < E_) {
    int run = 0;
    for (int i = 0; i < 256; ++i) { int v = cnt[i][tid]; cnt[i][tid] = run; run += v; }
    counts[tid*B_ + b] = run;
  }
  __syncthreads();
  int base[E_];
  #pragma unroll
  for (int e = 0; e < E_; ++e) base[e] = cnt[tid][e];
  for (int j = 0; j < PT; ++j) {
    int e = e_loc[j];
    int p = base[e]++;
    int s = tid*PT + j;
    if (p < CAP_) {
      pos_arr[(size_t)b*S_ + s] = p;
      slot_src[((size_t)e*B_ + b)*CAP_ + p] = s >> 1;
    } else {
      pos_arr[(size_t)b*S_ + s] = -1;
    }
  }
}

// ---------------- Transpose + fp32->bf16 ----------------
__global__ void transpose_conv_kernel(const float* __restrict__ in, unsigned short* __restrict__ out,
                                      int R, int Cc)
{
  __shared__ float tile[64][33];
  const int e = blockIdx.z;
  const float* ine = in + (size_t)e * R * Cc;
  unsigned short* oute = out + (size_t)e * R * Cc;
  const int c0 = blockIdx.x * 32, r0 = blockIdx.y * 64;
  const int tx = threadIdx.x & 7, ty = threadIdx.x >> 3;
  #pragma unroll
  for (int p = 0; p < 2; ++p) {
    const int rr = p*32 + ty;
    float4 v = *(const float4*)(ine + (size_t)(r0 + rr) * Cc + c0 + tx*4);
    tile[rr][tx*4+0] = v.x; tile[rr][tx*4+1] = v.y;
    tile[rr][tx*4+2] = v.z; tile[rr][tx*4+3] = v.w;
  }
  __syncthreads();
  short8 s;
  #pragma unroll
  for (int j = 0; j < 8; ++j) s[j] = (short)f2bf(tile[tx*8+j][ty]);
  *(short8*)(oute + (size_t)(c0 + ty) * R + r0 + tx*8) = s;
}

// ---------------- Dispatch ----------------
__global__ void dispatch_kernel(const float* __restrict__ x, const int* __restrict__ slot_src,
                                const int* __restrict__ counts, unsigned short* __restrict__ Xd,
                                int e_base, int nexp)
{
  int row = (int)((blockIdx.x * blockDim.x + threadIdx.x) >> 6);
  int lane = threadIdx.x & 63;
  int total = nexp * B_ * CAP_;
  if (row >= total) return;
  int el = row / (B_*CAP_);
  int rem = row - el*(B_*CAP_);
  int b = rem / CAP_, slot = rem - b*CAP_;
  int eg = e_base + el;
  int cnt = counts[eg*B_ + b]; if (cnt > CAP_) cnt = CAP_;
  unsigned short* orow = Xd + (size_t)row * C_;
  if (slot < cnt) {
    int t = slot_src[((size_t)eg*B_ + b)*CAP_ + slot];
    const float4* xr = (const float4*)(x + ((size_t)b*T_ + t)*C_);
    #pragma unroll
    for (int i = 0; i < C_/256; ++i) {
      float4 v = xr[i*64 + lane];
      ushort4 o;
      o.x = f2bf(v.x); o.y = f2bf(v.y); o.z = f2bf(v.z); o.w = f2bf(v.w);
      ((ushort4*)orow)[i*64 + lane] = o;
    }
  } else {
    ushort4 z; z.x = z.y = z.z = z.w = 0;
    #pragma unroll
    for (int i = 0; i < C_/256; ++i) ((ushort4*)orow)[i*64 + lane] = z;
  }
}

// ---------------- GEMM 256x256, BK=64, m201 4-phase/half-slot-ring schedule ----------------
// A [e][M][Kfull] bf16 x BT [e][N][Kfull] bf16 (+bias if non-null, opt relu) -> Out bf16.
// 512 threads = 8 waves (2M x 4N), per-wave 128x64 (8x4 16x16 frags, kk=2 K-halves).
// LDS 128KB: per operand a 4-slot ring of K-HALF tiles (256 rows x 32 shorts = 16KB).
// Half h = 2*tile+kk lives in slot h&3. Phases per tile:
//   P1: read B kk0 (4) + A m0-3 kk0 (4) | stage A(t+1,kk1) | bar | lgkm0 | prio1 16 MFMA prio0 | bar
//   P2: read A m4-7 kk0 (4)             | stage B(t+1,kk1) | bar | lgkm0 | prio1 16 MFMA prio0 | bar
//   P3: read B kk1 (4) + A m0-3 kk1 (4) | stage A(t+2,kk0) | bar | lgkm0 | prio1 16 MFMA prio0 | bar
//   P4: read A m4-7 kk1 (4)             | stage B(t+2,kk0) | bar | lgkm0 | prio1 16 MFMA prio0
//       | vmcnt(4) (0 near tail) | bar
// Ledger (proved): slot of half h re-staged exactly one phase after its readers'
// closing barrier; vmcnt(4)@P4 leaves only P3/P4's stages outstanding, so all of
// tile t+1 is published. Never drains to 0 until t+2==nk.
// Swizzle: 16B-chunk pos ^= (row&3) on BOTH staging source and ds_read (2-way
// bank aliasing = free, m136). LDS dest linear (rule #21).
template<int RELU>
__global__ __launch_bounds__(512) void gemm256_kernel(
    const unsigned short* __restrict__ A,
    const unsigned short* __restrict__ BT,
    const float* __restrict__ bias,
    unsigned short* __restrict__ Out0,
    unsigned short* __restrict__ Out1,
    int M, int N, int Kfull, int klen, int tilesPerSplit, int nwg)
{
  __shared__ __align__(16) unsigned short lds[65536]; // 128 KiB
  const int NT = N >> 8, MT = M >> 8;
  const int bid = blockIdx.x;
  const int wg = (bid & 7) * (nwg >> 3) + (bid >> 3);
  const int sp  = wg / tilesPerSplit;
  const int wgr = wg - sp * tilesPerSplit;
  const int e  = wgr / (MT*NT);
  const int r2 = wgr - e*(MT*NT);
  const int mt = r2 / NT, nt = r2 - mt*NT;
  const int k0 = sp * klen;
  const unsigned short* Ae = A + (size_t)e * M * Kfull;
  const unsigned short* Be = BT + (size_t)e * N * Kfull;
  const float* be = bias ? (bias + (size_t)e * N) : nullptr;
  unsigned short* Oe = (sp == 0 ? Out0 : Out1) + (size_t)e * M * N;
  const int m0 = mt*256, n0 = nt*256;

  const int tid = threadIdx.x, lane = tid & 63, w = tid >> 6;
  const int wr = w >> 2, wc = w & 3;   // 2 x 4 waves

  floatx4 acc[8][4];
  #pragma unroll
  for (int i = 0; i < 8; ++i)
    #pragma unroll
    for (int j = 0; j < 4; ++j) acc[i][j] = (floatx4){0.f, 0.f, 0.f, 0.f};

  // Staging: one K-half = 256 rows x 32 shorts = 1024 chunks of 16B; thread covers
  // chunks tid (rows 0-127) and 512+tid (rows 128-255). Chunk c -> row c>>2,
  // pos (c&3); pre-swizzled source pos' = (c&3)^(row&3).
  const int r0s = tid >> 2;           // 0..127
  const int p0s = ((tid & 3) ^ (r0s & 3)) * 8;   // shorts (same XOR for row+128)
  const unsigned short* gA0 = Ae + (size_t)(m0 + r0s)*Kfull + k0 + p0s;
  const unsigned short* gA1 = gA0 + (size_t)128*Kfull;
  const unsigned short* gB0 = Be + (size_t)(n0 + r0s)*Kfull + k0 + p0s;
  const unsigned short* gB1 = gB0 + (size_t)128*Kfull;
  const int la0 = w*512, la1 = 4096 + w*512;   // wave-uniform LDS bases (shorts)

  // Fragment reads: fr = lane&15 (row-in-frag), kq = lane>>4 (k-chunk 0..3).
  // row&3 == fr&3 (mf*16/wr*128/nf*16/wc*64 don't touch bits 0-1).
  const int fr = lane & 15, kq = lane >> 4;
  const int kqs = ((kq ^ (fr & 3)) * 8);
  const int aBase = (wr*128 + fr)*32 + kqs;            // + slot*8192 + mf*512
  const int bBase = 32768 + (wc*64 + fr)*32 + kqs;     // + slot*8192 + nf*512

  const int nk = klen >> 6;   // BK=64 tiles

#define STAGE_AH(h) do { int _s = (h)&3; size_t _k = (size_t)((h)>>1)*64 + ((h)&1)*32; \
    GLOAD16(gA0 + _k, lds + _s*8192 + la0); \
    GLOAD16(gA1 + _k, lds + _s*8192 + la1); } while(0)
#define STAGE_BH(h) do { int _s = (h)&3; size_t _k = (size_t)((h)>>1)*64 + ((h)&1)*32; \
    GLOAD16(gB0 + _k, lds + 32768 + _s*8192 + la0); \
    GLOAD16(gB1 + _k, lds + 32768 + _s*8192 + la1); } while(0)

  // prologue: tile0 kk0+kk1, tile1 kk0 (12 loads/thread)
  STAGE_AH(0); STAGE_BH(0);
  STAGE_AH(1); STAGE_BH(1);
  STAGE_AH(2); STAGE_BH(2);
  asm volatile("s_waitcnt vmcnt(4)" ::: "memory");   // tile0 landed
  BARRIER();

  for (int t = 0; t < nk; ++t) {
    const int s0 = (2*t) & 3, s1 = (2*t+1) & 3;
    const unsigned short* sA0 = lds + s0*8192;
    const unsigned short* sA1 = lds + s1*8192;
    short8 af[4], bfr[4];

    // ---- P1: B kk0 + A m0-3 kk0 | stage A(t+1,kk1) ----
    #pragma unroll
    for (int nf = 0; nf < 4; ++nf) bfr[nf] = *(const short8*)(sA0 + bBase + nf*512);
    #pragma unroll
    for (int mf = 0; mf < 4; ++mf) af[mf] = *(const short8*)(sA0 + aBase + mf*512);
    if (t + 1 < nk) STAGE_AH(2*(t+1)+1);
    BARRIER();
    asm volatile("s_waitcnt lgkmcnt(0)" ::: "memory");
    __builtin_amdgcn_s_setprio(1);
    #pragma unroll
    for (int mf = 0; mf < 4; ++mf)
      #pragma unroll
      for (int nf = 0; nf < 4; ++nf)
        acc[mf][nf] = __builtin_amdgcn_mfma_f32_16x16x32_bf16(af[mf], bfr[nf], acc[mf][nf], 0, 0, 0);
    __builtin_amdgcn_s_setprio(0);
    BARRIER();

    // ---- P2: A m4-7 kk0 | stage B(t+1,kk1) ----
    #pragma unroll
    for (int mf = 0; mf < 4; ++mf) af[mf] = *(const short8*)(sA0 + aBase + (mf+4)*512);
    if (t + 1 < nk) STAGE_BH(2*(t+1)+1);
    BARRIER();
    asm volatile("s_waitcnt lgkmcnt(0)" ::: "memory");
    __builtin_amdgcn_s_setprio(1);
    #pragma unroll
    for (int mf = 0; mf < 4; ++mf)
      #pragma unroll
      for (int nf = 0; nf < 4; ++nf)
        acc[mf+4][nf] = __builtin_amdgcn_mfma_f32_16x16x32_bf16(af[mf], bfr[nf], acc[mf+4][nf], 0, 0, 0);
    __builtin_amdgcn_s_setprio(0);
    BARRIER();

    // ---- P3: B kk1 + A m0-3 kk1 | stage A(t+2,kk0) ----
    #pragma unroll
    for (int nf = 0; nf < 4; ++nf) bfr[nf] = *(const short8*)(sA1 + bBase + nf*512);
    #pragma unroll
    for (int mf = 0; mf < 4; ++mf) af[mf] = *(const short8*)(sA1 + aBase + mf*512);
    if (t + 2 < nk) STAGE_AH(2*(t+2));
    BARRIER();
    asm volatile("s_waitcnt lgkmcnt(0)" ::: "memory");
    __builtin_amdgcn_s_setprio(1);
    #pragma unroll
    for (int mf = 0; mf < 4; ++mf)
      #pragma unroll
      for (int nf = 0; nf < 4; ++nf)
        acc[mf][nf] = __builtin_amdgcn_mfma_f32_16x16x32_bf16(af[mf], bfr[nf], acc[mf][nf], 0, 0, 0);
    __builtin_amdgcn_s_setprio(0);
    BARRIER();

    // ---- P4: A m4-7 kk1 | stage B(t+2,kk0) ----
    #pragma unroll
    for (int mf = 0; mf < 4; ++mf) af[mf] = *(const short8*)(sA1 + aBase + (mf+4)*512);
    if (t + 2 < nk) STAGE_BH(2*(t+2));
    BARRIER();
    asm volatile("s_waitcnt lgkmcnt(0)" ::: "memory");
    __builtin_amdgcn_s_setprio(1);
    #pragma unroll
    for (int mf = 0; mf < 4; ++mf)
      #pragma unroll
      for (int nf = 0; nf < 4; ++nf)
        acc[mf+4][nf] = __builtin_amdgcn_mfma_f32_16x16x32_bf16(af[mf], bfr[nf], acc[mf+4][nf], 0, 0, 0);
    __builtin_amdgcn_s_setprio(0);

    // tile boundary: publish tile t+1 (counted; 0 only near tail)
    if (t + 1 < nk) {
      if (t + 2 < nk) asm volatile("s_waitcnt vmcnt(4)" ::: "memory");
      else            asm volatile("s_waitcnt vmcnt(0)" ::: "memory");
      BARRIER();
    }
  }
#undef STAGE_AH
#undef STAGE_BH

  // epilogue: C/D layout col = lane&15, row = (lane>>4)*4 + reg
  const int col = lane & 15, rbase = (lane >> 4) * 4;
  #pragma unroll
  for (int mf = 0; mf < 8; ++mf) {
    const int gr0 = m0 + wr*128 + mf*16 + rbase;
    #pragma unroll
    for (int nf = 0; nf < 4; ++nf) {
      const int gc = n0 + wc*64 + nf*16 + col;
      const float bv = be ? be[gc] : 0.f;
      #pragma unroll
      for (int r = 0; r < 4; ++r) {
        float v = acc[mf][nf][r] + bv;
        if (RELU) v = fmaxf(v, 0.f);
        Oe[(size_t)(gr0 + r)*N + gc] = f2bf(v);
      }
    }
  }
}

// ---------------- Combine ----------------
__global__ void combine_kernel(const unsigned short* __restrict__ Y0,
                               const unsigned short* __restrict__ Y1,
                               const float* __restrict__ b2c,
                               const int* __restrict__ topk_e, const float* __restrict__ topk_p,
                               const int* __restrict__ pos_arr, float* __restrict__ out)
{
  int token = (int)((blockIdx.x * blockDim.x + threadIdx.x) >> 6);
  int lane = threadIdx.x & 63;
  if (token >= NTOK) return;
  int b = token / T_, t = token - b*T_;
  int s0 = b*S_ + t*2;
  float acc[16];
  #pragma unroll
  for (int i = 0; i < 16; ++i) acc[i] = 0.f;
  #pragma unroll
  for (int k = 0; k < 2; ++k) {
    int pos = pos_arr[s0 + k];
    if (pos < 0) continue;
    int e = topk_e[s0 + k];
    float p = topk_p[s0 + k];
    size_t rowoff = (((size_t)e*B_ + b)*CAP_ + pos) * C_;
    const unsigned short* yr0 = Y0 + rowoff;
    const unsigned short* yr1 = Y1 ? (Y1 + rowoff) : nullptr;
    const float* bb = b2c ? (b2c + (size_t)e * C_) : nullptr;
    #pragma unroll
    for (int i = 0; i < 4; ++i) {
      ushort4 v = ((const ushort4*)yr0)[i*64 + lane];
      float s0v = bf2f(v.x), s1v = bf2f(v.y), s2v = bf2f(v.z), s3v = bf2f(v.w);
      if (yr1) {
        ushort4 u = ((const ushort4*)yr1)[i*64 + lane];
        s0v += bf2f(u.x); s1v += bf2f(u.y); s2v += bf2f(u.z); s3v += bf2f(u.w);
      }
      if (bb) {
        float4 bv = ((const float4*)bb)[i*64 + lane];
        s0v += bv.x; s1v += bv.y; s2v += bv.z; s3v += bv.w;
      }
      acc[i*4+0] += p * s0v;
      acc[i*4+1] += p * s1v;
      acc[i*4+2] += p * s2v;
      acc[i*4+3] += p * s3v;
    }
  }
  float4* orow = (float4*)(out + (size_t)token * C_);
  #pragma unroll
  for (int i = 0; i < 4; ++i) {
    float4 o;
    o.x = acc[i*4+0]; o.y = acc[i*4+1]; o.z = acc[i*4+2]; o.w = acc[i*4+3];
    orow[i*64 + lane] = o;
  }
}

extern "C" void kernel_launch(void* const* d_in, const int* in_sizes, int n_in,
                              void* d_out, int out_size, void* d_ws, size_t ws_size,
                              hipStream_t stream)
{
  const float* x  = (const float*)d_in[0];
  const float* Wg = (const float*)d_in[1];
  const float* bg = (const float*)d_in[2];
  const float* W1 = (const float*)d_in[3];
  const float* b1 = (const float*)d_in[4];
  const float* W2 = (const float*)d_in[5];
  const float* b2 = (const float*)d_in[6];
  float* out = (float*)d_out;

  char* ws = (char*)d_ws;
  size_t off = 0;
  auto alloc = [&](size_t bytes) -> char* {
    char* p = ws + off;
    off = (off + bytes + 255) & ~(size_t)255;
    return p;
  };
  int*   topk_e  = (int*)  alloc((size_t)NTOK * K_ * 4);
  float* topk_p  = (float*)alloc((size_t)NTOK * K_ * 4);
  int*   pos_arr = (int*)  alloc((size_t)B_ * S_ * 4);
  int*   slot_src= (int*)  alloc((size_t)E_ * B_ * CAP_ * 4);
  int*   counts  = (int*)  alloc((size_t)E_ * B_ * 4);
  unsigned short* Ybuf = (unsigned short*)alloc((size_t)E_ * ROWS_PER_E * C_ * 2);
  size_t fixed = off;
  const size_t perE = (size_t)C_ * DFF_ * 2
                    + (size_t)ROWS_PER_E * C_ * 2
                    + (size_t)ROWS_PER_E * DFF_ * 2
                    + 3 * 256;
  int k = 8;
  while (k > 1 && fixed + (size_t)k * perE > ws_size) k >>= 1;
  unsigned short* Wt = (unsigned short*)alloc((size_t)k * C_ * DFF_ * 2);
  unsigned short* Xd = (unsigned short*)alloc((size_t)k * ROWS_PER_E * C_ * 2);
  unsigned short* Hb = (unsigned short*)alloc((size_t)k * ROWS_PER_E * DFF_ * 2);

  router_kernel<<<NTOK/4, 256, 0, stream>>>(x, Wg, bg, topk_e, topk_p);
  scan_kernel<<<B_, 256, 0, stream>>>(topk_e, pos_arr, slot_src, counts);

  const bool splitK2 = (k == 8);

  for (int eb = 0; eb < E_; eb += k) {
    transpose_conv_kernel<<<dim3(DFF_/32, C_/64, k), 256, 0, stream>>>(
        W1 + (size_t)eb * C_ * DFF_, Wt, C_, DFF_);
    dispatch_kernel<<<(k * ROWS_PER_E) / 4, 256, 0, stream>>>(x, slot_src, counts, Xd, eb, k);
    // H = relu(Xd @ W1 + b1)
    {
      int tiles = k * (ROWS_PER_E/256) * (DFF_/256);
      gemm256_kernel<1><<<tiles, 512, 0, stream>>>(
          Xd, Wt, b1 + (size_t)eb * DFF_, Hb, Hb, ROWS_PER_E, DFF_, C_, C_, tiles, tiles);
    }
    transpose_conv_kernel<<<dim3(C_/32, DFF_/64, k), 256, 0, stream>>>(
        W2 + (size_t)eb * DFF_ * C_, Wt, DFF_, C_);
    // Y = H @ W2
    {
      int tiles = k * (ROWS_PER_E/256) * (C_/256);
      if (splitK2) {
        gemm256_kernel<0><<<2*tiles, 512, 0, stream>>>(
            Hb, Wt, nullptr, Ybuf, Xd, ROWS_PER_E, C_, DFF_, DFF_/2, tiles, 2*tiles);
      } else {
        gemm256_kernel<0><<<tiles, 512, 0, stream>>>(
            Hb, Wt, b2 + (size_t)eb * C_, Ybuf + (size_t)eb * ROWS_PER_E * C_,
            Ybuf + (size_t)eb * ROWS_PER_E * C_, ROWS_PER_E, C_, DFF_, DFF_, tiles, tiles);
      }
    }
  }

  combine_kernel<<<NTOK/4, 256, 0, stream>>>(
      Ybuf, splitK2 ? Xd : nullptr, splitK2 ? b2 : nullptr,
      topk_e, topk_p, pos_arr, out);
}

// Round 10
// 578.546 us; speedup vs baseline: 1.0899x; 1.0300x over previous
//
#include <hip/hip_runtime.h>
#include <stdint.h>

#define B_ 8
#define T_ 2048
#define C_ 1024
#define E_ 8
#define K_ 2
#define CAP_ 320
#define DFF_ 4096
#define S_ (T_*K_)
#define NTOK (B_*T_)
#define ROWS_PER_E (B_*CAP_) // 2560

typedef __attribute__((ext_vector_type(8))) short short8;
typedef __attribute__((ext_vector_type(4))) float floatx4;

__device__ __forceinline__ unsigned short f2bf(float f) {
  union { float f; unsigned u; } v; v.f = f;
  unsigned r = v.u + 0x7fffu + ((v.u >> 16) & 1u);
  return (unsigned short)(r >> 16);
}
__device__ __forceinline__ float bf2f(unsigned short h) {
  union { unsigned u; float f; } v; v.u = ((unsigned)h) << 16;
  return v.f;
}

#define GLOAD16(g, l) __builtin_amdgcn_global_load_lds( \
    (const __attribute__((address_space(1))) void*)(g), \
    (__attribute__((address_space(3))) void*)(l), 16, 0, 0)

#define BARRIER() asm volatile("s_barrier" ::: "memory")

// ---------------- Router: fp64 logits, softmax, top-2 ----------------
__global__ void router_kernel(const float* __restrict__ x, const float* __restrict__ Wg,
                              const float* __restrict__ bg,
                              int* __restrict__ topk_e, float* __restrict__ topk_p)
{
  int token = (int)((blockIdx.x * blockDim.x + threadIdx.x) >> 6);
  int lane = threadIdx.x & 63;
  if (token >= NTOK) return;
  const float* xr = x + (size_t)token * C_;
  double acc[E_];
  #pragma unroll
  for (int e = 0; e < E_; ++e) acc[e] = 0.0;
  for (int c = lane; c < C_; c += 64) {
    double xv = (double)xr[c];
    const float4* w4 = (const float4*)(Wg + (size_t)c * E_);
    float4 wa = w4[0], wb = w4[1];
    acc[0] += xv * (double)wa.x; acc[1] += xv * (double)wa.y;
    acc[2] += xv * (double)wa.z; acc[3] += xv * (double)wa.w;
    acc[4] += xv * (double)wb.x; acc[5] += xv * (double)wb.y;
    acc[6] += xv * (double)wb.z; acc[7] += xv * (double)wb.w;
  }
  #pragma unroll
  for (int off = 32; off; off >>= 1) {
    #pragma unroll
    for (int e = 0; e < E_; ++e) acc[e] += __shfl_down(acc[e], off, 64);
  }
  if (lane == 0) {
    double lg[E_];
    double mx = -1e300;
    #pragma unroll
    for (int e = 0; e < E_; ++e) { lg[e] = acc[e] + (double)bg[e]; mx = fmax(mx, lg[e]); }
    double se = 0.0, pr[E_];
    #pragma unroll
    for (int e = 0; e < E_; ++e) { pr[e] = exp(lg[e] - mx); se += pr[e]; }
    #pragma unroll
    for (int e = 0; e < E_; ++e) pr[e] /= se;
    int e0 = 0;
    #pragma unroll
    for (int e = 1; e < E_; ++e) if (pr[e] > pr[e0]) e0 = e;
    int e1 = -1;
    #pragma unroll
    for (int e = 0; e < E_; ++e) {
      if (e == e0) continue;
      if (e1 < 0 || pr[e] > pr[e1]) e1 = e;
    }
    topk_e[token*2+0] = e0; topk_p[token*2+0] = (float)pr[e0];
    topk_e[token*2+1] = e1; topk_p[token*2+1] = (float)pr[e1];
  }
}

// ---------------- Scan ----------------
__global__ void scan_kernel(const int* __restrict__ topk_e,
                            int* __restrict__ pos_arr, int* __restrict__ slot_src,
                            int* __restrict__ counts)
{
  const int b = blockIdx.x;
  const int tid = threadIdx.x;
  const int PT = S_ / 256; // 16
  __shared__ int cnt[256][E_];
  int e_loc[16];
  int local[E_];
  #pragma unroll
  for (int e = 0; e < E_; ++e) local[e] = 0;
  const int* te = topk_e + (size_t)b * S_;
  for (int j = 0; j < PT; ++j) {
    int e = te[tid*PT + j];
    e_loc[j] = e;
    local[e]++;
  }
  #pragma unroll
  for (int e = 0; e < E_; ++e) cnt[tid][e] = local[e];
  __syncthreads();
  if (tid < E_) {
    int run = 0;
    for (int i = 0; i < 256; ++i) { int v = cnt[i][tid]; cnt[i][tid] = run; run += v; }
    counts[tid*B_ + b] = run;
  }
  __syncthreads();
  int base[E_];
  #pragma unroll
  for (int e = 0; e < E_; ++e) base[e] = cnt[tid][e];
  for (int j = 0; j < PT; ++j) {
    int e = e_loc[j];
    int p = base[e]++;
    int s = tid*PT + j;
    if (p < CAP_) {
      pos_arr[(size_t)b*S_ + s] = p;
      slot_src[((size_t)e*B_ + b)*CAP_ + p] = s >> 1;
    } else {
      pos_arr[(size_t)b*S_ + s] = -1;
    }
  }
}

// ---------------- Transpose + fp32->bf16 ----------------
__global__ void transpose_conv_kernel(const float* __restrict__ in, unsigned short* __restrict__ out,
                                      int R, int Cc)
{
  __shared__ float tile[64][33];
  const int e = blockIdx.z;
  const float* ine = in + (size_t)e * R * Cc;
  unsigned short* oute = out + (size_t)e * R * Cc;
  const int c0 = blockIdx.x * 32, r0 = blockIdx.y * 64;
  const int tx = threadIdx.x & 7, ty = threadIdx.x >> 3;
  #pragma unroll
  for (int p = 0; p < 2; ++p) {
    const int rr = p*32 + ty;
    float4 v = *(const float4*)(ine + (size_t)(r0 + rr) * Cc + c0 + tx*4);
    tile[rr][tx*4+0] = v.x; tile[rr][tx*4+1] = v.y;
    tile[rr][tx*4+2] = v.z; tile[rr][tx*4+3] = v.w;
  }
  __syncthreads();
  short8 s;
  #pragma unroll
  for (int j = 0; j < 8; ++j) s[j] = (short)f2bf(tile[tx*8+j][ty]);
  *(short8*)(oute + (size_t)(c0 + ty) * R + r0 + tx*8) = s;
}

// ---------------- Dispatch ----------------
__global__ void dispatch_kernel(const float* __restrict__ x, const int* __restrict__ slot_src,
                                const int* __restrict__ counts, unsigned short* __restrict__ Xd,
                                int e_base, int nexp)
{
  int row = (int)((blockIdx.x * blockDim.x + threadIdx.x) >> 6);
  int lane = threadIdx.x & 63;
  int total = nexp * B_ * CAP_;
  if (row >= total) return;
  int el = row / (B_*CAP_);
  int rem = row - el*(B_*CAP_);
  int b = rem / CAP_, slot = rem - b*CAP_;
  int eg = e_base + el;
  int cnt = counts[eg*B_ + b]; if (cnt > CAP_) cnt = CAP_;
  unsigned short* orow = Xd + (size_t)row * C_;
  if (slot < cnt) {
    int t = slot_src[((size_t)eg*B_ + b)*CAP_ + slot];
    const float4* xr = (const float4*)(x + ((size_t)b*T_ + t)*C_);
    #pragma unroll
    for (int i = 0; i < C_/256; ++i) {
      float4 v = xr[i*64 + lane];
      ushort4 o;
      o.x = f2bf(v.x); o.y = f2bf(v.y); o.z = f2bf(v.z); o.w = f2bf(v.w);
      ((ushort4*)orow)[i*64 + lane] = o;
    }
  } else {
    ushort4 z; z.x = z.y = z.z = z.w = 0;
    #pragma unroll
    for (int i = 0; i < C_/256; ++i) ((ushort4*)orow)[i*64 + lane] = z;
  }
}

// ---------------- GEMM 256x256, BK=64, 4-phase/half-slot-ring, FIXED T2 swizzle ----------------
// A [e][M][Kfull] bf16 x BT [e][N][Kfull] bf16 (+bias if non-null, opt relu) -> Out bf16.
// 512 threads = 8 waves (2M x 4N), per-wave 128x64 (8x4 16x16 frags, kk=2 K-halves).
// LDS 128KB: per operand a 4-slot ring of K-HALF tiles (256 rows x 32 shorts = 16KB).
// Half h = 2*tile+kk lives in slot h&3. 4 phases/tile, 1 half-stage per phase,
// vmcnt(4) once per tile at P4 (0 only near tail). Ledger proved in round 8.
// T2 swizzle (PROVEN 0-conflict, rounds 4-6): 16B-chunk ^= ((row>>1)&3), applied
// to BOTH the staging source k-offset and the ds_read k-offset; LDS dest linear
// (rule #21). Bank proof: slot = 4*(row&1) + (kq^((row>>1)&3)) -> each of 8 slots
// hit by exactly 2 of 16 rows -> 2-way = free (m136). Round 9's (row&3) variant
// was 4-way-conflicted (1.57e7 measured) - this is the one-line fix.
template<int RELU>
__global__ __launch_bounds__(512) void gemm256_kernel(
    const unsigned short* __restrict__ A,
    const unsigned short* __restrict__ BT,
    const float* __restrict__ bias,
    unsigned short* __restrict__ Out0,
    unsigned short* __restrict__ Out1,
    int M, int N, int Kfull, int klen, int tilesPerSplit, int nwg)
{
  __shared__ __align__(16) unsigned short lds[65536]; // 128 KiB
  const int NT = N >> 8, MT = M >> 8;
  const int bid = blockIdx.x;
  const int wg = (bid & 7) * (nwg >> 3) + (bid >> 3);
  const int sp  = wg / tilesPerSplit;
  const int wgr = wg - sp * tilesPerSplit;
  const int e  = wgr / (MT*NT);
  const int r2 = wgr - e*(MT*NT);
  const int mt = r2 / NT, nt = r2 - mt*NT;
  const int k0 = sp * klen;
  const unsigned short* Ae = A + (size_t)e * M * Kfull;
  const unsigned short* Be = BT + (size_t)e * N * Kfull;
  const float* be = bias ? (bias + (size_t)e * N) : nullptr;
  unsigned short* Oe = (sp == 0 ? Out0 : Out1) + (size_t)e * M * N;
  const int m0 = mt*256, n0 = nt*256;

  const int tid = threadIdx.x, lane = tid & 63, w = tid >> 6;
  const int wr = w >> 2, wc = w & 3;   // 2 x 4 waves

  floatx4 acc[8][4];
  #pragma unroll
  for (int i = 0; i < 8; ++i)
    #pragma unroll
    for (int j = 0; j < 4; ++j) acc[i][j] = (floatx4){0.f, 0.f, 0.f, 0.f};

  // Staging: one K-half = 256 rows x 32 shorts = 1024 chunks of 16B; thread covers
  // chunks tid (rows 0-127) and 512+tid (rows 128-255, same XOR: +128 is row bit 7).
  // Chunk c -> row c>>2, pos (c&3); pre-swizzled source pos' = (c&3)^((row>>1)&3).
  const int r0s = tid >> 2;           // 0..127
  const int p0s = ((tid & 3) ^ ((r0s >> 1) & 3)) * 8;   // shorts
  const unsigned short* gA0 = Ae + (size_t)(m0 + r0s)*Kfull + k0 + p0s;
  const unsigned short* gA1 = gA0 + (size_t)128*Kfull;
  const unsigned short* gB0 = Be + (size_t)(n0 + r0s)*Kfull + k0 + p0s;
  const unsigned short* gB1 = gB0 + (size_t)128*Kfull;
  const int la0 = w*512, la1 = 4096 + w*512;   // wave-uniform LDS bases (shorts)

  // Fragment reads: fr = lane&15 (row-in-frag), kq = lane>>4 (k-chunk 0..3).
  // (row>>1)&3 == (fr>>1)&3: mf*16/wr*128/nf*16/wc*64 only touch row bits >=4... 
  // (wc*64: bit 6+; nf*16: bit 4+; all leave bits 1-2 = fr bits 1-2).
  const int fr = lane & 15, kq = lane >> 4;
  const int kqs = ((kq ^ ((fr >> 1) & 3)) * 8);
  const int aBase = (wr*128 + fr)*32 + kqs;            // + slot*8192 + mf*512
  const int bBase = 32768 + (wc*64 + fr)*32 + kqs;     // + slot*8192 + nf*512

  const int nk = klen >> 6;   // BK=64 tiles

#define STAGE_AH(h) do { int _s = (h)&3; size_t _k = (size_t)((h)>>1)*64 + ((h)&1)*32; \
    GLOAD16(gA0 + _k, lds + _s*8192 + la0); \
    GLOAD16(gA1 + _k, lds + _s*8192 + la1); } while(0)
#define STAGE_BH(h) do { int _s = (h)&3; size_t _k = (size_t)((h)>>1)*64 + ((h)&1)*32; \
    GLOAD16(gB0 + _k, lds + 32768 + _s*8192 + la0); \
    GLOAD16(gB1 + _k, lds + 32768 + _s*8192 + la1); } while(0)

  // prologue: tile0 kk0+kk1, tile1 kk0 (12 loads/thread)
  STAGE_AH(0); STAGE_BH(0);
  STAGE_AH(1); STAGE_BH(1);
  STAGE_AH(2); STAGE_BH(2);
  asm volatile("s_waitcnt vmcnt(4)" ::: "memory");   // tile0 landed
  BARRIER();

  for (int t = 0; t < nk; ++t) {
    const int s0 = (2*t) & 3, s1 = (2*t+1) & 3;
    const unsigned short* sA0 = lds + s0*8192;
    const unsigned short* sA1 = lds + s1*8192;
    short8 af[4], bfr[4];

    // ---- P1: B kk0 + A m0-3 kk0 | stage A(t+1,kk1) ----
    #pragma unroll
    for (int nf = 0; nf < 4; ++nf) bfr[nf] = *(const short8*)(sA0 + bBase + nf*512);
    #pragma unroll
    for (int mf = 0; mf < 4; ++mf) af[mf] = *(const short8*)(sA0 + aBase + mf*512);
    if (t + 1 < nk) STAGE_AH(2*(t+1)+1);
    BARRIER();
    asm volatile("s_waitcnt lgkmcnt(0)" ::: "memory");
    __builtin_amdgcn_s_setprio(1);
    #pragma unroll
    for (int mf = 0; mf < 4; ++mf)
      #pragma unroll
      for (int nf = 0; nf < 4; ++nf)
        acc[mf][nf] = __builtin_amdgcn_mfma_f32_16x16x32_bf16(af[mf], bfr[nf], acc[mf][nf], 0, 0, 0);
    __builtin_amdgcn_s_setprio(0);
    BARRIER();

    // ---- P2: A m4-7 kk0 | stage B(t+1,kk1) ----
    #pragma unroll
    for (int mf = 0; mf < 4; ++mf) af[mf] = *(const short8*)(sA0 + aBase + (mf+4)*512);
    if (t + 1 < nk) STAGE_BH(2*(t+1)+1);
    BARRIER();
    asm volatile("s_waitcnt lgkmcnt(0)" ::: "memory");
    __builtin_amdgcn_s_setprio(1);
    #pragma unroll
    for (int mf = 0; mf < 4; ++mf)
      #pragma unroll
      for (int nf = 0; nf < 4; ++nf)
        acc[mf+4][nf] = __builtin_amdgcn_mfma_f32_16x16x32_bf16(af[mf], bfr[nf], acc[mf+4][nf], 0, 0, 0);
    __builtin_amdgcn_s_setprio(0);
    BARRIER();

    // ---- P3: B kk1 + A m0-3 kk1 | stage A(t+2,kk0) ----
    #pragma unroll
    for (int nf = 0; nf < 4; ++nf) bfr[nf] = *(const short8*)(sA1 + bBase + nf*512);
    #pragma unroll
    for (int mf = 0; mf < 4; ++mf) af[mf] = *(const short8*)(sA1 + aBase + mf*512);
    if (t + 2 < nk) STAGE_AH(2*(t+2));
    BARRIER();
    asm volatile("s_waitcnt lgkmcnt(0)" ::: "memory");
    __builtin_amdgcn_s_setprio(1);
    #pragma unroll
    for (int mf = 0; mf < 4; ++mf)
      #pragma unroll
      for (int nf = 0; nf < 4; ++nf)
        acc[mf][nf] = __builtin_amdgcn_mfma_f32_16x16x32_bf16(af[mf], bfr[nf], acc[mf][nf], 0, 0, 0);
    __builtin_amdgcn_s_setprio(0);
    BARRIER();

    // ---- P4: A m4-7 kk1 | stage B(t+2,kk0) ----
    #pragma unroll
    for (int mf = 0; mf < 4; ++mf) af[mf] = *(const short8*)(sA1 + aBase + (mf+4)*512);
    if (t + 2 < nk) STAGE_BH(2*(t+2));
    BARRIER();
    asm volatile("s_waitcnt lgkmcnt(0)" ::: "memory");
    __builtin_amdgcn_s_setprio(1);
    #pragma unroll
    for (int mf = 0; mf < 4; ++mf)
      #pragma unroll
      for (int nf = 0; nf < 4; ++nf)
        acc[mf+4][nf] = __builtin_amdgcn_mfma_f32_16x16x32_bf16(af[mf], bfr[nf], acc[mf+4][nf], 0, 0, 0);
    __builtin_amdgcn_s_setprio(0);

    // tile boundary: publish tile t+1 (counted; 0 only near tail)
    if (t + 1 < nk) {
      if (t + 2 < nk) asm volatile("s_waitcnt vmcnt(4)" ::: "memory");
      else            asm volatile("s_waitcnt vmcnt(0)" ::: "memory");
      BARRIER();
    }
  }
#undef STAGE_AH
#undef STAGE_BH

  // epilogue: C/D layout col = lane&15, row = (lane>>4)*4 + reg
  const int col = lane & 15, rbase = (lane >> 4) * 4;
  #pragma unroll
  for (int mf = 0; mf < 8; ++mf) {
    const int gr0 = m0 + wr*128 + mf*16 + rbase;
    #pragma unroll
    for (int nf = 0; nf < 4; ++nf) {
      const int gc = n0 + wc*64 + nf*16 + col;
      const float bv = be ? be[gc] : 0.f;
      #pragma unroll
      for (int r = 0; r < 4; ++r) {
        float v = acc[mf][nf][r] + bv;
        if (RELU) v = fmaxf(v, 0.f);
        Oe[(size_t)(gr0 + r)*N + gc] = f2bf(v);
      }
    }
  }
}

// ---------------- Combine ----------------
__global__ void combine_kernel(const unsigned short* __restrict__ Y0,
                               const unsigned short* __restrict__ Y1,
                               const float* __restrict__ b2c,
                               const int* __restrict__ topk_e, const float* __restrict__ topk_p,
                               const int* __restrict__ pos_arr, float* __restrict__ out)
{
  int token = (int)((blockIdx.x * blockDim.x + threadIdx.x) >> 6);
  int lane = threadIdx.x & 63;
  if (token >= NTOK) return;
  int b = token / T_, t = token - b*T_;
  int s0 = b*S_ + t*2;
  float acc[16];
  #pragma unroll
  for (int i = 0; i < 16; ++i) acc[i] = 0.f;
  #pragma unroll
  for (int k = 0; k < 2; ++k) {
    int pos = pos_arr[s0 + k];
    if (pos < 0) continue;
    int e = topk_e[s0 + k];
    float p = topk_p[s0 + k];
    size_t rowoff = (((size_t)e*B_ + b)*CAP_ + pos) * C_;
    const unsigned short* yr0 = Y0 + rowoff;
    const unsigned short* yr1 = Y1 ? (Y1 + rowoff) : nullptr;
    const float* bb = b2c ? (b2c + (size_t)e * C_) : nullptr;
    #pragma unroll
    for (int i = 0; i < 4; ++i) {
      ushort4 v = ((const ushort4*)yr0)[i*64 + lane];
      float s0v = bf2f(v.x), s1v = bf2f(v.y), s2v = bf2f(v.z), s3v = bf2f(v.w);
      if (yr1) {
        ushort4 u = ((const ushort4*)yr1)[i*64 + lane];
        s0v += bf2f(u.x); s1v += bf2f(u.y); s2v += bf2f(u.z); s3v += bf2f(u.w);
      }
      if (bb) {
        float4 bv = ((const float4*)bb)[i*64 + lane];
        s0v += bv.x; s1v += bv.y; s2v += bv.z; s3v += bv.w;
      }
      acc[i*4+0] += p * s0v;
      acc[i*4+1] += p * s1v;
      acc[i*4+2] += p * s2v;
      acc[i*4+3] += p * s3v;
    }
  }
  float4* orow = (float4*)(out + (size_t)token * C_);
  #pragma unroll
  for (int i = 0; i < 4; ++i) {
    float4 o;
    o.x = acc[i*4+0]; o.y = acc[i*4+1]; o.z = acc[i*4+2]; o.w = acc[i*4+3];
    orow[i*64 + lane] = o;
  }
}

extern "C" void kernel_launch(void* const* d_in, const int* in_sizes, int n_in,
                              void* d_out, int out_size, void* d_ws, size_t ws_size,
                              hipStream_t stream)
{
  const float* x  = (const float*)d_in[0];
  const float* Wg = (const float*)d_in[1];
  const float* bg = (const float*)d_in[2];
  const float* W1 = (const float*)d_in[3];
  const float* b1 = (const float*)d_in[4];
  const float* W2 = (const float*)d_in[5];
  const float* b2 = (const float*)d_in[6];
  float* out = (float*)d_out;

  char* ws = (char*)d_ws;
  size_t off = 0;
  auto alloc = [&](size_t bytes) -> char* {
    char* p = ws + off;
    off = (off + bytes + 255) & ~(size_t)255;
    return p;
  };
  int*   topk_e  = (int*)  alloc((size_t)NTOK * K_ * 4);
  float* topk_p  = (float*)alloc((size_t)NTOK * K_ * 4);
  int*   pos_arr = (int*)  alloc((size_t)B_ * S_ * 4);
  int*   slot_src= (int*)  alloc((size_t)E_ * B_ * CAP_ * 4);
  int*   counts  = (int*)  alloc((size_t)E_ * B_ * 4);
  unsigned short* Ybuf = (unsigned short*)alloc((size_t)E_ * ROWS_PER_E * C_ * 2);
  size_t fixed = off;
  const size_t perE = (size_t)C_ * DFF_ * 2
                    + (size_t)ROWS_PER_E * C_ * 2
                    + (size_t)ROWS_PER_E * DFF_ * 2
                    + 3 * 256;
  int k = 8;
  while (k > 1 && fixed + (size_t)k * perE > ws_size) k >>= 1;
  unsigned short* Wt = (unsigned short*)alloc((size_t)k * C_ * DFF_ * 2);
  unsigned short* Xd = (unsigned short*)alloc((size_t)k * ROWS_PER_E * C_ * 2);
  unsigned short* Hb = (unsigned short*)alloc((size_t)k * ROWS_PER_E * DFF_ * 2);

  router_kernel<<<NTOK/4, 256, 0, stream>>>(x, Wg, bg, topk_e, topk_p);
  scan_kernel<<<B_, 256, 0, stream>>>(topk_e, pos_arr, slot_src, counts);

  const bool splitK2 = (k == 8);

  for (int eb = 0; eb < E_; eb += k) {
    transpose_conv_kernel<<<dim3(DFF_/32, C_/64, k), 256, 0, stream>>>(
        W1 + (size_t)eb * C_ * DFF_, Wt, C_, DFF_);
    dispatch_kernel<<<(k * ROWS_PER_E) / 4, 256, 0, stream>>>(x, slot_src, counts, Xd, eb, k);
    // H = relu(Xd @ W1 + b1)
    {
      int tiles = k * (ROWS_PER_E/256) * (DFF_/256);
      gemm256_kernel<1><<<tiles, 512, 0, stream>>>(
          Xd, Wt, b1 + (size_t)eb * DFF_, Hb, Hb, ROWS_PER_E, DFF_, C_, C_, tiles, tiles);
    }
    transpose_conv_kernel<<<dim3(C_/32, DFF_/64, k), 256, 0, stream>>>(
        W2 + (size_t)eb * DFF_ * C_, Wt, DFF_, C_);
    // Y = H @ W2
    {
      int tiles = k * (ROWS_PER_E/256) * (C_/256);
      if (splitK2) {
        gemm256_kernel<0><<<2*tiles, 512, 0, stream>>>(
            Hb, Wt, nullptr, Ybuf, Xd, ROWS_PER_E, C_, DFF_, DFF_/2, tiles, 2*tiles);
      } else {
        gemm256_kernel<0><<<tiles, 512, 0, stream>>>(
            Hb, Wt, b2 + (size_t)eb * C_, Ybuf + (size_t)eb * ROWS_PER_E * C_,
            Ybuf + (size_t)eb * ROWS_PER_E * C_, ROWS_PER_E, C_, DFF_, DFF_, tiles, tiles);
      }
    }
  }

  combine_kernel<<<NTOK/4, 256, 0, stream>>>(
      Ybuf, splitK2 ? Xd : nullptr, splitK2 ? b2 : nullptr,
      topk_e, topk_p, pos_arr, out);
}

// Round 11
// 569.991 us; speedup vs baseline: 1.1063x; 1.0150x over previous
//
#include <hip/hip_runtime.h>
#include <stdint.h>

#define B_ 8
#define T_ 2048
#define C_ 1024
#define E_ 8
#define K_ 2
#define CAP_ 320
#define DFF_ 4096
#define S_ (T_*K_)
#define NTOK (B_*T_)
#define ROWS_PER_E (B_*CAP_) // 2560

typedef __attribute__((ext_vector_type(8))) short short8;
typedef __attribute__((ext_vector_type(4))) float floatx4;

__device__ __forceinline__ unsigned short f2bf(float f) {
  union { float f; unsigned u; } v; v.f = f;
  unsigned r = v.u + 0x7fffu + ((v.u >> 16) & 1u);
  return (unsigned short)(r >> 16);
}
__device__ __forceinline__ float bf2f(unsigned short h) {
  union { unsigned u; float f; } v; v.u = ((unsigned)h) << 16;
  return v.f;
}

#define GLOAD16(g, l) __builtin_amdgcn_global_load_lds( \
    (const __attribute__((address_space(1))) void*)(g), \
    (__attribute__((address_space(3))) void*)(l), 16, 0, 0)

#define BARRIER() asm volatile("s_barrier" ::: "memory")
#define SCHEDB() __builtin_amdgcn_sched_barrier(0)

// ---------------- Router: fp64 logits, softmax, top-2 ----------------
__global__ void router_kernel(const float* __restrict__ x, const float* __restrict__ Wg,
                              const float* __restrict__ bg,
                              int* __restrict__ topk_e, float* __restrict__ topk_p)
{
  int token = (int)((blockIdx.x * blockDim.x + threadIdx.x) >> 6);
  int lane = threadIdx.x & 63;
  if (token >= NTOK) return;
  const float* xr = x + (size_t)token * C_;
  double acc[E_];
  #pragma unroll
  for (int e = 0; e < E_; ++e) acc[e] = 0.0;
  for (int c = lane; c < C_; c += 64) {
    double xv = (double)xr[c];
    const float4* w4 = (const float4*)(Wg + (size_t)c * E_);
    float4 wa = w4[0], wb = w4[1];
    acc[0] += xv * (double)wa.x; acc[1] += xv * (double)wa.y;
    acc[2] += xv * (double)wa.z; acc[3] += xv * (double)wa.w;
    acc[4] += xv * (double)wb.x; acc[5] += xv * (double)wb.y;
    acc[6] += xv * (double)wb.z; acc[7] += xv * (double)wb.w;
  }
  #pragma unroll
  for (int off = 32; off; off >>= 1) {
    #pragma unroll
    for (int e = 0; e < E_; ++e) acc[e] += __shfl_down(acc[e], off, 64);
  }
  if (lane == 0) {
    double lg[E_];
    double mx = -1e300;
    #pragma unroll
    for (int e = 0; e < E_; ++e) { lg[e] = acc[e] + (double)bg[e]; mx = fmax(mx, lg[e]); }
    double se = 0.0, pr[E_];
    #pragma unroll
    for (int e = 0; e < E_; ++e) { pr[e] = exp(lg[e] - mx); se += pr[e]; }
    #pragma unroll
    for (int e = 0; e < E_; ++e) pr[e] /= se;
    int e0 = 0;
    #pragma unroll
    for (int e = 1; e < E_; ++e) if (pr[e] > pr[e0]) e0 = e;
    int e1 = -1;
    #pragma unroll
    for (int e = 0; e < E_; ++e) {
      if (e == e0) continue;
      if (e1 < 0 || pr[e] > pr[e1]) e1 = e;
    }
    topk_e[token*2+0] = e0; topk_p[token*2+0] = (float)pr[e0];
    topk_e[token*2+1] = e1; topk_p[token*2+1] = (float)pr[e1];
  }
}

// ---------------- Scan ----------------
__global__ void scan_kernel(const int* __restrict__ topk_e,
                            int* __restrict__ pos_arr, int* __restrict__ slot_src,
                            int* __restrict__ counts)
{
  const int b = blockIdx.x;
  const int tid = threadIdx.x;
  const int PT = S_ / 256; // 16
  __shared__ int cnt[256][E_];
  int e_loc[16];
  int local[E_];
  #pragma unroll
  for (int e = 0; e < E_; ++e) local[e] = 0;
  const int* te = topk_e + (size_t)b * S_;
  for (int j = 0; j < PT; ++j) {
    int e = te[tid*PT + j];
    e_loc[j] = e;
    local[e]++;
  }
  #pragma unroll
  for (int e = 0; e < E_; ++e) cnt[tid][e] = local[e];
  __syncthreads();
  if (tid < E_) {
    int run = 0;
    for (int i = 0; i < 256; ++i) { int v = cnt[i][tid]; cnt[i][tid] = run; run += v; }
    counts[tid*B_ + b] = run;
  }
  __syncthreads();
  int base[E_];
  #pragma unroll
  for (int e = 0; e < E_; ++e) base[e] = cnt[tid][e];
  for (int j = 0; j < PT; ++j) {
    int e = e_loc[j];
    int p = base[e]++;
    int s = tid*PT + j;
    if (p < CAP_) {
      pos_arr[(size_t)b*S_ + s] = p;
      slot_src[((size_t)e*B_ + b)*CAP_ + p] = s >> 1;
    } else {
      pos_arr[(size_t)b*S_ + s] = -1;
    }
  }
}

// ---------------- Transpose + fp32->bf16 ----------------
__global__ void transpose_conv_kernel(const float* __restrict__ in, unsigned short* __restrict__ out,
                                      int R, int Cc)
{
  __shared__ float tile[64][33];
  const int e = blockIdx.z;
  const float* ine = in + (size_t)e * R * Cc;
  unsigned short* oute = out + (size_t)e * R * Cc;
  const int c0 = blockIdx.x * 32, r0 = blockIdx.y * 64;
  const int tx = threadIdx.x & 7, ty = threadIdx.x >> 3;
  #pragma unroll
  for (int p = 0; p < 2; ++p) {
    const int rr = p*32 + ty;
    float4 v = *(const float4*)(ine + (size_t)(r0 + rr) * Cc + c0 + tx*4);
    tile[rr][tx*4+0] = v.x; tile[rr][tx*4+1] = v.y;
    tile[rr][tx*4+2] = v.z; tile[rr][tx*4+3] = v.w;
  }
  __syncthreads();
  short8 s;
  #pragma unroll
  for (int j = 0; j < 8; ++j) s[j] = (short)f2bf(tile[tx*8+j][ty]);
  *(short8*)(oute + (size_t)(c0 + ty) * R + r0 + tx*8) = s;
}

// ---------------- Dispatch ----------------
__global__ void dispatch_kernel(const float* __restrict__ x, const int* __restrict__ slot_src,
                                const int* __restrict__ counts, unsigned short* __restrict__ Xd,
                                int e_base, int nexp)
{
  int row = (int)((blockIdx.x * blockDim.x + threadIdx.x) >> 6);
  int lane = threadIdx.x & 63;
  int total = nexp * B_ * CAP_;
  if (row >= total) return;
  int el = row / (B_*CAP_);
  int rem = row - el*(B_*CAP_);
  int b = rem / CAP_, slot = rem - b*CAP_;
  int eg = e_base + el;
  int cnt = counts[eg*B_ + b]; if (cnt > CAP_) cnt = CAP_;
  unsigned short* orow = Xd + (size_t)row * C_;
  if (slot < cnt) {
    int t = slot_src[((size_t)eg*B_ + b)*CAP_ + slot];
    const float4* xr = (const float4*)(x + ((size_t)b*T_ + t)*C_);
    #pragma unroll
    for (int i = 0; i < C_/256; ++i) {
      float4 v = xr[i*64 + lane];
      ushort4 o;
      o.x = f2bf(v.x); o.y = f2bf(v.y); o.z = f2bf(v.z); o.w = f2bf(v.w);
      ((ushort4*)orow)[i*64 + lane] = o;
    }
  } else {
    ushort4 z; z.x = z.y = z.z = z.w = 0;
    #pragma unroll
    for (int i = 0; i < C_/256; ++i) ((ushort4*)orow)[i*64 + lane] = z;
  }
}

// ---------------- GEMM 256x256, BK=64, pipelined-fragment 4-quadrant schedule ----------------
// A [e][M][Kfull] bf16 x BT [e][N][Kfull] bf16 (+bias if non-null, opt relu) -> Out bf16.
// 512 threads = 8 waves (2M x 4N), per-wave 128x64 (8x4 16x16 frags, kk=2 K-halves).
// LDS 128KB: per operand a 4-slot ring of K-HALF tiles (256 rows x 32 shorts = 16KB);
// half h = 2*tile+kk in slot h&3. KEY CHANGE vs r10: fragment ds_reads are issued
// one quadrant AHEAD with counted lgkmcnt(4/8/4/0), so each 16-MFMA cluster runs
// WHILE the next cluster's reads are in flight (LDS pipe overlaps MFMA pipe).
// Only 2 barriers/tile:
//   - WAR fence at P2 (after lgkmcnt(8) every wave's half-2t reads are complete;
//     P3/P4 re-stage that slot with halves (t+2,kk0))
//   - publish barrier at P4 with counted vmcnt(4) (never 0 until t+2==nk).
// Ledger: stages P1/P2 -> (t+1,kk1), P3/P4 -> (t+2,kk0). Boundary vmcnt(4) at
// iter t drains (t-1)'s P3/P4 + t's P1/P2 => halves 2t+2, 2t+3 (= all of tile t+1)
// published before iter t+1 reads them. Prologue stages halves 0,1,2; vmcnt(4)
// publishes tile 0.
// T2 swizzle (0-conflict, verified r10): 16B-chunk ^= ((row>>1)&3) on BOTH the
// staging source and ds_read offsets; LDS dest linear (rule #21).
template<int RELU>
__global__ __launch_bounds__(512) void gemm256_kernel(
    const unsigned short* __restrict__ A,
    const unsigned short* __restrict__ BT,
    const float* __restrict__ bias,
    unsigned short* __restrict__ Out0,
    unsigned short* __restrict__ Out1,
    int M, int N, int Kfull, int klen, int tilesPerSplit, int nwg)
{
  __shared__ __align__(16) unsigned short lds[65536]; // 128 KiB
  const int NT = N >> 8, MT = M >> 8;
  const int bid = blockIdx.x;
  const int wg = (bid & 7) * (nwg >> 3) + (bid >> 3);
  const int sp  = wg / tilesPerSplit;
  const int wgr = wg - sp * tilesPerSplit;
  const int e  = wgr / (MT*NT);
  const int r2 = wgr - e*(MT*NT);
  const int mt = r2 / NT, nt = r2 - mt*NT;
  const int k0 = sp * klen;
  const unsigned short* Ae = A + (size_t)e * M * Kfull;
  const unsigned short* Be = BT + (size_t)e * N * Kfull;
  const float* be = bias ? (bias + (size_t)e * N) : nullptr;
  unsigned short* Oe = (sp == 0 ? Out0 : Out1) + (size_t)e * M * N;
  const int m0 = mt*256, n0 = nt*256;

  const int tid = threadIdx.x, lane = tid & 63, w = tid >> 6;
  const int wr = w >> 2, wc = w & 3;   // 2 x 4 waves

  floatx4 acc[8][4];
  #pragma unroll
  for (int i = 0; i < 8; ++i)
    #pragma unroll
    for (int j = 0; j < 4; ++j) acc[i][j] = (floatx4){0.f, 0.f, 0.f, 0.f};

  // Staging: one K-half = 256 rows x 32 shorts = 1024 chunks of 16B; thread covers
  // chunks tid (rows 0-127) and 512+tid (rows 128-255; +128 = row bit 7, XOR same).
  const int r0s = tid >> 2;           // 0..127
  const int p0s = ((tid & 3) ^ ((r0s >> 1) & 3)) * 8;   // shorts
  const unsigned short* gA0 = Ae + (size_t)(m0 + r0s)*Kfull + k0 + p0s;
  const unsigned short* gA1 = gA0 + (size_t)128*Kfull;
  const unsigned short* gB0 = Be + (size_t)(n0 + r0s)*Kfull + k0 + p0s;
  const unsigned short* gB1 = gB0 + (size_t)128*Kfull;
  const int la0 = w*512, la1 = 4096 + w*512;   // wave-uniform LDS bases (shorts)

  // Fragment reads: fr = lane&15, kq = lane>>4; (row>>1)&3 == (fr>>1)&3.
  const int fr = lane & 15, kq = lane >> 4;
  const int kqs = ((kq ^ ((fr >> 1) & 3)) * 8);
  const int aBase = (wr*128 + fr)*32 + kqs;            // + slot*8192 + mf*512
  const int bBase = 32768 + (wc*64 + fr)*32 + kqs;     // + slot*8192 + nf*512

  const int nk = klen >> 6;   // BK=64 tiles

#define STAGE_AH(h) do { int _s = (h)&3; size_t _k = (size_t)((h)>>1)*64 + ((h)&1)*32; \
    GLOAD16(gA0 + _k, lds + _s*8192 + la0); \
    GLOAD16(gA1 + _k, lds + _s*8192 + la1); } while(0)
#define STAGE_BH(h) do { int _s = (h)&3; size_t _k = (size_t)((h)>>1)*64 + ((h)&1)*32; \
    GLOAD16(gB0 + _k, lds + 32768 + _s*8192 + la0); \
    GLOAD16(gB1 + _k, lds + 32768 + _s*8192 + la1); } while(0)

  // prologue: halves 0,1 (tile 0) + half 2 (tile 1 kk0): 12 loads/thread
  STAGE_AH(0); STAGE_BH(0);
  STAGE_AH(1); STAGE_BH(1);
  STAGE_AH(2); STAGE_BH(2);
  asm volatile("s_waitcnt vmcnt(4)" ::: "memory");   // tile 0 (halves 0,1) landed
  BARRIER();

  for (int t = 0; t < nk; ++t) {
    const int s0 = (2*t) & 3, s1 = (2*t+1) & 3;
    const unsigned short* sA0 = lds + s0*8192;
    const unsigned short* sA1 = lds + s1*8192;
    short8 rB0[4], rA0lo[4], rA0hi[4], rB1[4], rA1lo[4], rA1hi[4];

    // ---- P1: issue rB0+rA0lo (8) | rA0hi (4); stage A(t+1,kk1); MFMA Q1 under rA0hi ----
    #pragma unroll
    for (int nf = 0; nf < 4; ++nf) rB0[nf] = *(const short8*)(sA0 + bBase + nf*512);
    #pragma unroll
    for (int mf = 0; mf < 4; ++mf) rA0lo[mf] = *(const short8*)(sA0 + aBase + mf*512);
    SCHEDB();
    #pragma unroll
    for (int mf = 0; mf < 4; ++mf) rA0hi[mf] = *(const short8*)(sA0 + aBase + (mf+4)*512);
    if (t + 1 < nk) STAGE_AH(2*t+3);
    SCHEDB();
    asm volatile("s_waitcnt lgkmcnt(4)" ::: "memory");  // rB0,rA0lo ready; rA0hi flying
    SCHEDB();
    __builtin_amdgcn_s_setprio(1);
    #pragma unroll
    for (int mf = 0; mf < 4; ++mf)
      #pragma unroll
      for (int nf = 0; nf < 4; ++nf)
        acc[mf][nf] = __builtin_amdgcn_mfma_f32_16x16x32_bf16(rA0lo[mf], rB0[nf], acc[mf][nf], 0, 0, 0);
    __builtin_amdgcn_s_setprio(0);
    SCHEDB();

    // ---- P2: issue rB1+rA1lo (8); stage B(t+1,kk1); WAR barrier; MFMA Q2 under them ----
    #pragma unroll
    for (int nf = 0; nf < 4; ++nf) rB1[nf] = *(const short8*)(sA1 + bBase + nf*512);
    #pragma unroll
    for (int mf = 0; mf < 4; ++mf) rA1lo[mf] = *(const short8*)(sA1 + aBase + mf*512);
    if (t + 1 < nk) STAGE_BH(2*t+3);
    SCHEDB();
    asm volatile("s_waitcnt lgkmcnt(8)" ::: "memory");  // rA0hi ready (all half-2t reads done)
    SCHEDB();
    BARRIER();   // WAR: every wave's half-2t reads complete -> P3/P4 may re-stage slot s0
    __builtin_amdgcn_s_setprio(1);
    #pragma unroll
    for (int mf = 0; mf < 4; ++mf)
      #pragma unroll
      for (int nf = 0; nf < 4; ++nf)
        acc[mf+4][nf] = __builtin_amdgcn_mfma_f32_16x16x32_bf16(rA0hi[mf], rB0[nf], acc[mf+4][nf], 0, 0, 0);
    __builtin_amdgcn_s_setprio(0);
    SCHEDB();

    // ---- P3: issue rA1hi (4); stage A(t+2,kk0); MFMA Q3 under rA1hi ----
    #pragma unroll
    for (int mf = 0; mf < 4; ++mf) rA1hi[mf] = *(const short8*)(sA1 + aBase + (mf+4)*512);
    if (t + 2 < nk) STAGE_AH(2*t+4);
    SCHEDB();
    asm volatile("s_waitcnt lgkmcnt(4)" ::: "memory");  // rB1,rA1lo ready; rA1hi flying
    SCHEDB();
    __builtin_amdgcn_s_setprio(1);
    #pragma unroll
    for (int mf = 0; mf < 4; ++mf)
      #pragma unroll
      for (int nf = 0; nf < 4; ++nf)
        acc[mf][nf] = __builtin_amdgcn_mfma_f32_16x16x32_bf16(rA1lo[mf], rB1[nf], acc[mf][nf], 0, 0, 0);
    __builtin_amdgcn_s_setprio(0);
    SCHEDB();

    // ---- P4: stage B(t+2,kk0); MFMA Q4; publish boundary ----
    if (t + 2 < nk) STAGE_BH(2*t+4);
    SCHEDB();
    asm volatile("s_waitcnt lgkmcnt(0)" ::: "memory");  // rA1hi ready
    SCHEDB();
    __builtin_amdgcn_s_setprio(1);
    #pragma unroll
    for (int mf = 0; mf < 4; ++mf)
      #pragma unroll
      for (int nf = 0; nf < 4; ++nf)
        acc[mf+4][nf] = __builtin_amdgcn_mfma_f32_16x16x32_bf16(rA1hi[mf], rB1[nf], acc[mf+4][nf], 0, 0, 0);
    __builtin_amdgcn_s_setprio(0);
    SCHEDB();

    if (t + 1 < nk) {
      if (t + 2 < nk) asm volatile("s_waitcnt vmcnt(4)" ::: "memory");
      else            asm volatile("s_waitcnt vmcnt(0)" ::: "memory");
      BARRIER();   // tile t+1 (halves 2t+2, 2t+3) published
    }
  }
#undef STAGE_AH
#undef STAGE_BH

  // epilogue: C/D layout col = lane&15, row = (lane>>4)*4 + reg
  const int col = lane & 15, rbase = (lane >> 4) * 4;
  #pragma unroll
  for (int mf = 0; mf < 8; ++mf) {
    const int gr0 = m0 + wr*128 + mf*16 + rbase;
    #pragma unroll
    for (int nf = 0; nf < 4; ++nf) {
      const int gc = n0 + wc*64 + nf*16 + col;
      const float bv = be ? be[gc] : 0.f;
      #pragma unroll
      for (int r = 0; r < 4; ++r) {
        float v = acc[mf][nf][r] + bv;
        if (RELU) v = fmaxf(v, 0.f);
        Oe[(size_t)(gr0 + r)*N + gc] = f2bf(v);
      }
    }
  }
}

// ---------------- Combine ----------------
__global__ void combine_kernel(const unsigned short* __restrict__ Y0,
                               const unsigned short* __restrict__ Y1,
                               const float* __restrict__ b2c,
                               const int* __restrict__ topk_e, const float* __restrict__ topk_p,
                               const int* __restrict__ pos_arr, float* __restrict__ out)
{
  int token = (int)((blockIdx.x * blockDim.x + threadIdx.x) >> 6);
  int lane = threadIdx.x & 63;
  if (token >= NTOK) return;
  int b = token / T_, t = token - b*T_;
  int s0 = b*S_ + t*2;
  float acc[16];
  #pragma unroll
  for (int i = 0; i < 16; ++i) acc[i] = 0.f;
  #pragma unroll
  for (int k = 0; k < 2; ++k) {
    int pos = pos_arr[s0 + k];
    if (pos < 0) continue;
    int e = topk_e[s0 + k];
    float p = topk_p[s0 + k];
    size_t rowoff = (((size_t)e*B_ + b)*CAP_ + pos) * C_;
    const unsigned short* yr0 = Y0 + rowoff;
    const unsigned short* yr1 = Y1 ? (Y1 + rowoff) : nullptr;
    const float* bb = b2c ? (b2c + (size_t)e * C_) : nullptr;
    #pragma unroll
    for (int i = 0; i < 4; ++i) {
      ushort4 v = ((const ushort4*)yr0)[i*64 + lane];
      float s0v = bf2f(v.x), s1v = bf2f(v.y), s2v = bf2f(v.z), s3v = bf2f(v.w);
      if (yr1) {
        ushort4 u = ((const ushort4*)yr1)[i*64 + lane];
        s0v += bf2f(u.x); s1v += bf2f(u.y); s2v += bf2f(u.z); s3v += bf2f(u.w);
      }
      if (bb) {
        float4 bv = ((const float4*)bb)[i*64 + lane];
        s0v += bv.x; s1v += bv.y; s2v += bv.z; s3v += bv.w;
      }
      acc[i*4+0] += p * s0v;
      acc[i*4+1] += p * s1v;
      acc[i*4+2] += p * s2v;
      acc[i*4+3] += p * s3v;
    }
  }
  float4* orow = (float4*)(out + (size_t)token * C_);
  #pragma unroll
  for (int i = 0; i < 4; ++i) {
    float4 o;
    o.x = acc[i*4+0]; o.y = acc[i*4+1]; o.z = acc[i*4+2]; o.w = acc[i*4+3];
    orow[i*64 + lane] = o;
  }
}

extern "C" void kernel_launch(void* const* d_in, const int* in_sizes, int n_in,
                              void* d_out, int out_size, void* d_ws, size_t ws_size,
                              hipStream_t stream)
{
  const float* x  = (const float*)d_in[0];
  const float* Wg = (const float*)d_in[1];
  const float* bg = (const float*)d_in[2];
  const float* W1 = (const float*)d_in[3];
  const float* b1 = (const float*)d_in[4];
  const float* W2 = (const float*)d_in[5];
  const float* b2 = (const float*)d_in[6];
  float* out = (float*)d_out;

  char* ws = (char*)d_ws;
  size_t off = 0;
  auto alloc = [&](size_t bytes) -> char* {
    char* p = ws + off;
    off = (off + bytes + 255) & ~(size_t)255;
    return p;
  };
  int*   topk_e  = (int*)  alloc((size_t)NTOK * K_ * 4);
  float* topk_p  = (float*)alloc((size_t)NTOK * K_ * 4);
  int*   pos_arr = (int*)  alloc((size_t)B_ * S_ * 4);
  int*   slot_src= (int*)  alloc((size_t)E_ * B_ * CAP_ * 4);
  int*   counts  = (int*)  alloc((size_t)E_ * B_ * 4);
  unsigned short* Ybuf = (unsigned short*)alloc((size_t)E_ * ROWS_PER_E * C_ * 2);
  size_t fixed = off;
  const size_t perE = (size_t)C_ * DFF_ * 2
                    + (size_t)ROWS_PER_E * C_ * 2
                    + (size_t)ROWS_PER_E * DFF_ * 2
                    + 3 * 256;
  int k = 8;
  while (k > 1 && fixed + (size_t)k * perE > ws_size) k >>= 1;
  unsigned short* Wt = (unsigned short*)alloc((size_t)k * C_ * DFF_ * 2);
  unsigned short* Xd = (unsigned short*)alloc((size_t)k * ROWS_PER_E * C_ * 2);
  unsigned short* Hb = (unsigned short*)alloc((size_t)k * ROWS_PER_E * DFF_ * 2);

  router_kernel<<<NTOK/4, 256, 0, stream>>>(x, Wg, bg, topk_e, topk_p);
  scan_kernel<<<B_, 256, 0, stream>>>(topk_e, pos_arr, slot_src, counts);

  const bool splitK2 = (k == 8);

  for (int eb = 0; eb < E_; eb += k) {
    transpose_conv_kernel<<<dim3(DFF_/32, C_/64, k), 256, 0, stream>>>(
        W1 + (size_t)eb * C_ * DFF_, Wt, C_, DFF_);
    dispatch_kernel<<<(k * ROWS_PER_E) / 4, 256, 0, stream>>>(x, slot_src, counts, Xd, eb, k);
    // H = relu(Xd @ W1 + b1)
    {
      int tiles = k * (ROWS_PER_E/256) * (DFF_/256);
      gemm256_kernel<1><<<tiles, 512, 0, stream>>>(
          Xd, Wt, b1 + (size_t)eb * DFF_, Hb, Hb, ROWS_PER_E, DFF_, C_, C_, tiles, tiles);
    }
    transpose_conv_kernel<<<dim3(C_/32, DFF_/64, k), 256, 0, stream>>>(
        W2 + (size_t)eb * DFF_ * C_, Wt, DFF_, C_);
    // Y = H @ W2
    {
      int tiles = k * (ROWS_PER_E/256) * (C_/256);
      if (splitK2) {
        gemm256_kernel<0><<<2*tiles, 512, 0, stream>>>(
            Hb, Wt, nullptr, Ybuf, Xd, ROWS_PER_E, C_, DFF_, DFF_/2, tiles, 2*tiles);
      } else {
        gemm256_kernel<0><<<tiles, 512, 0, stream>>>(
            Hb, Wt, b2 + (size_t)eb * C_, Ybuf + (size_t)eb * ROWS_PER_E * C_,
            Ybuf + (size_t)eb * ROWS_PER_E * C_, ROWS_PER_E, C_, DFF_, DFF_, tiles, tiles);
      }
    }
  }

  combine_kernel<<<NTOK/4, 256, 0, stream>>>(
      Ybuf, splitK2 ? Xd : nullptr, splitK2 ? b2 : nullptr,
      topk_e, topk_p, pos_arr, out);
}

// Round 12
// 567.382 us; speedup vs baseline: 1.1114x; 1.0046x over previous
//
#include <hip/hip_runtime.h>
#include <stdint.h>

#define B_ 8
#define T_ 2048
#define C_ 1024
#define E_ 8
#define K_ 2
#define CAP_ 320
#define DFF_ 4096
#define S_ (T_*K_)
#define NTOK (B_*T_)
#define ROWS_PER_E (B_*CAP_) // 2560

typedef __attribute__((ext_vector_type(8))) short short8;
typedef __attribute__((ext_vector_type(4))) float floatx4;

__device__ __forceinline__ unsigned short f2bf(float f) {
  union { float f; unsigned u; } v; v.f = f;
  unsigned r = v.u + 0x7fffu + ((v.u >> 16) & 1u);
  return (unsigned short)(r >> 16);
}
__device__ __forceinline__ float bf2f(unsigned short h) {
  union { unsigned u; float f; } v; v.u = ((unsigned)h) << 16;
  return v.f;
}

#define GLOAD16(g, l) __builtin_amdgcn_global_load_lds( \
    (const __attribute__((address_space(1))) void*)(g), \
    (__attribute__((address_space(3))) void*)(l), 16, 0, 0)

#define BARRIER() asm volatile("s_barrier" ::: "memory")
#define SCHEDB() __builtin_amdgcn_sched_barrier(0)

// ---------------- Router: fp64 logits, softmax, top-2 ----------------
__global__ void router_kernel(const float* __restrict__ x, const float* __restrict__ Wg,
                              const float* __restrict__ bg,
                              int* __restrict__ topk_e, float* __restrict__ topk_p)
{
  int token = (int)((blockIdx.x * blockDim.x + threadIdx.x) >> 6);
  int lane = threadIdx.x & 63;
  if (token >= NTOK) return;
  const float* xr = x + (size_t)token * C_;
  double acc[E_];
  #pragma unroll
  for (int e = 0; e < E_; ++e) acc[e] = 0.0;
  for (int c = lane; c < C_; c += 64) {
    double xv = (double)xr[c];
    const float4* w4 = (const float4*)(Wg + (size_t)c * E_);
    float4 wa = w4[0], wb = w4[1];
    acc[0] += xv * (double)wa.x; acc[1] += xv * (double)wa.y;
    acc[2] += xv * (double)wa.z; acc[3] += xv * (double)wa.w;
    acc[4] += xv * (double)wb.x; acc[5] += xv * (double)wb.y;
    acc[6] += xv * (double)wb.z; acc[7] += xv * (double)wb.w;
  }
  #pragma unroll
  for (int off = 32; off; off >>= 1) {
    #pragma unroll
    for (int e = 0; e < E_; ++e) acc[e] += __shfl_down(acc[e], off, 64);
  }
  if (lane == 0) {
    double lg[E_];
    double mx = -1e300;
    #pragma unroll
    for (int e = 0; e < E_; ++e) { lg[e] = acc[e] + (double)bg[e]; mx = fmax(mx, lg[e]); }
    double se = 0.0, pr[E_];
    #pragma unroll
    for (int e = 0; e < E_; ++e) { pr[e] = exp(lg[e] - mx); se += pr[e]; }
    #pragma unroll
    for (int e = 0; e < E_; ++e) pr[e] /= se;
    int e0 = 0;
    #pragma unroll
    for (int e = 1; e < E_; ++e) if (pr[e] > pr[e0]) e0 = e;
    int e1 = -1;
    #pragma unroll
    for (int e = 0; e < E_; ++e) {
      if (e == e0) continue;
      if (e1 < 0 || pr[e] > pr[e1]) e1 = e;
    }
    topk_e[token*2+0] = e0; topk_p[token*2+0] = (float)pr[e0];
    topk_e[token*2+1] = e1; topk_p[token*2+1] = (float)pr[e1];
  }
}

// ---------------- Scan ----------------
__global__ void scan_kernel(const int* __restrict__ topk_e,
                            int* __restrict__ pos_arr, int* __restrict__ slot_src,
                            int* __restrict__ counts)
{
  const int b = blockIdx.x;
  const int tid = threadIdx.x;
  const int PT = S_ / 256; // 16
  __shared__ int cnt[256][E_];
  int e_loc[16];
  int local[E_];
  #pragma unroll
  for (int e = 0; e < E_; ++e) local[e] = 0;
  const int* te = topk_e + (size_t)b * S_;
  for (int j = 0; j < PT; ++j) {
    int e = te[tid*PT + j];
    e_loc[j] = e;
    local[e]++;
  }
  #pragma unroll
  for (int e = 0; e < E_; ++e) cnt[tid][e] = local[e];
  __syncthreads();
  if (tid < E_) {
    int run = 0;
    for (int i = 0; i < 256; ++i) { int v = cnt[i][tid]; cnt[i][tid] = run; run += v; }
    counts[tid*B_ + b] = run;
  }
  __syncthreads();
  int base[E_];
  #pragma unroll
  for (int e = 0; e < E_; ++e) base[e] = cnt[tid][e];
  for (int j = 0; j < PT; ++j) {
    int e = e_loc[j];
    int p = base[e]++;
    int s = tid*PT + j;
    if (p < CAP_) {
      pos_arr[(size_t)b*S_ + s] = p;
      slot_src[((size_t)e*B_ + b)*CAP_ + p] = s >> 1;
    } else {
      pos_arr[(size_t)b*S_ + s] = -1;
    }
  }
}

// ---------------- Transpose + fp32->bf16 ----------------
__global__ void transpose_conv_kernel(const float* __restrict__ in, unsigned short* __restrict__ out,
                                      int R, int Cc)
{
  __shared__ float tile[64][33];
  const int e = blockIdx.z;
  const float* ine = in + (size_t)e * R * Cc;
  unsigned short* oute = out + (size_t)e * R * Cc;
  const int c0 = blockIdx.x * 32, r0 = blockIdx.y * 64;
  const int tx = threadIdx.x & 7, ty = threadIdx.x >> 3;
  #pragma unroll
  for (int p = 0; p < 2; ++p) {
    const int rr = p*32 + ty;
    float4 v = *(const float4*)(ine + (size_t)(r0 + rr) * Cc + c0 + tx*4);
    tile[rr][tx*4+0] = v.x; tile[rr][tx*4+1] = v.y;
    tile[rr][tx*4+2] = v.z; tile[rr][tx*4+3] = v.w;
  }
  __syncthreads();
  short8 s;
  #pragma unroll
  for (int j = 0; j < 8; ++j) s[j] = (short)f2bf(tile[tx*8+j][ty]);
  *(short8*)(oute + (size_t)(c0 + ty) * R + r0 + tx*8) = s;
}

// ---------------- Dispatch ----------------
__global__ void dispatch_kernel(const float* __restrict__ x, const int* __restrict__ slot_src,
                                const int* __restrict__ counts, unsigned short* __restrict__ Xd,
                                int e_base, int nexp)
{
  int row = (int)((blockIdx.x * blockDim.x + threadIdx.x) >> 6);
  int lane = threadIdx.x & 63;
  int total = nexp * B_ * CAP_;
  if (row >= total) return;
  int el = row / (B_*CAP_);
  int rem = row - el*(B_*CAP_);
  int b = rem / CAP_, slot = rem - b*CAP_;
  int eg = e_base + el;
  int cnt = counts[eg*B_ + b]; if (cnt > CAP_) cnt = CAP_;
  unsigned short* orow = Xd + (size_t)row * C_;
  if (slot < cnt) {
    int t = slot_src[((size_t)eg*B_ + b)*CAP_ + slot];
    const float4* xr = (const float4*)(x + ((size_t)b*T_ + t)*C_);
    #pragma unroll
    for (int i = 0; i < C_/256; ++i) {
      float4 v = xr[i*64 + lane];
      ushort4 o;
      o.x = f2bf(v.x); o.y = f2bf(v.y); o.z = f2bf(v.z); o.w = f2bf(v.w);
      ((ushort4*)orow)[i*64 + lane] = o;
    }
  } else {
    ushort4 z; z.x = z.y = z.z = z.w = 0;
    #pragma unroll
    for (int i = 0; i < C_/256; ++i) ((ushort4*)orow)[i*64 + lane] = z;
  }
}

// ---------------- GEMM 256x256, BK=64, mod-5 half-ring, ONE barrier/tile ----------------
// A [e][M][Kfull] bf16 x BT [e][N][Kfull] bf16 (+bias if non-null, opt relu) -> Out bf16.
// 512 threads = 8 waves (2M x 4N), per-wave 128x64 (8x4 16x16 frags, kk=2 K-halves).
// LDS 160KB: per operand a 5-SLOT ring of K-HALF tiles (256 rows x 32 shorts = 16KB);
// half h lives in slot h%5. mod-5 makes every stage target a slot whose half was
// fully read in tile t-1 (all reads retire before the t-1 boundary barrier via
// each wave's P4 lgkmcnt(0)) -> NO mid-tile WAR barrier needed. One barrier/tile.
// Register pipeline (from r11): fragment ds_reads issued one quadrant ahead with
// counted lgkmcnt(4/8/4/0) so MFMA clusters run while next reads are in flight.
// Stages: P1 A(2t+3), P2 B(2t+3), P3 A(2t+4), P4 B(2t+4); boundary vmcnt(4)
// drains exactly halves 2t+2,2t+3 (= tile t+1); never 0 until t+2==nk.
// T2 swizzle (0-conflict, verified r10/r11): 16B-chunk ^= ((row>>1)&3) on BOTH
// staging source and ds_read offsets; LDS dest linear (rule #21).
template<int RELU>
__global__ __launch_bounds__(512) void gemm256_kernel(
    const unsigned short* __restrict__ A,
    const unsigned short* __restrict__ BT,
    const float* __restrict__ bias,
    unsigned short* __restrict__ Out0,
    unsigned short* __restrict__ Out1,
    int M, int N, int Kfull, int klen, int tilesPerSplit, int nwg)
{
  __shared__ __align__(16) unsigned short lds[81920]; // 160 KiB: A 5x8192, B 5x8192 shorts
  const int NT = N >> 8, MT = M >> 8;
  const int bid = blockIdx.x;
  const int wg = (bid & 7) * (nwg >> 3) + (bid >> 3);
  const int sp  = wg / tilesPerSplit;
  const int wgr = wg - sp * tilesPerSplit;
  const int e  = wgr / (MT*NT);
  const int r2 = wgr - e*(MT*NT);
  const int mt = r2 / NT, nt = r2 - mt*NT;
  const int k0 = sp * klen;
  const unsigned short* Ae = A + (size_t)e * M * Kfull;
  const unsigned short* Be = BT + (size_t)e * N * Kfull;
  const float* be = bias ? (bias + (size_t)e * N) : nullptr;
  unsigned short* Oe = (sp == 0 ? Out0 : Out1) + (size_t)e * M * N;
  const int m0 = mt*256, n0 = nt*256;

  const int tid = threadIdx.x, lane = tid & 63, w = tid >> 6;
  const int wr = w >> 2, wc = w & 3;   // 2 x 4 waves

  floatx4 acc[8][4];
  #pragma unroll
  for (int i = 0; i < 8; ++i)
    #pragma unroll
    for (int j = 0; j < 4; ++j) acc[i][j] = (floatx4){0.f, 0.f, 0.f, 0.f};

  // Staging: one K-half = 256 rows x 32 shorts = 1024 chunks of 16B; thread covers
  // chunks tid (rows 0-127) and 512+tid (rows 128-255; +128 = row bit 7, XOR same).
  const int r0s = tid >> 2;           // 0..127
  const int p0s = ((tid & 3) ^ ((r0s >> 1) & 3)) * 8;   // shorts
  const unsigned short* gA0 = Ae + (size_t)(m0 + r0s)*Kfull + k0 + p0s;
  const unsigned short* gA1 = gA0 + (size_t)128*Kfull;
  const unsigned short* gB0 = Be + (size_t)(n0 + r0s)*Kfull + k0 + p0s;
  const unsigned short* gB1 = gB0 + (size_t)128*Kfull;
  const int la0 = w*512, la1 = 4096 + w*512;   // wave-uniform LDS bases (shorts)

  // Fragment reads: fr = lane&15, kq = lane>>4; (row>>1)&3 == (fr>>1)&3.
  const int fr = lane & 15, kq = lane >> 4;
  const int kqs = ((kq ^ ((fr >> 1) & 3)) * 8);
  const int aBase = (wr*128 + fr)*32 + kqs;            // + slot*8192 + mf*512
  const int bBase = 40960 + (wc*64 + fr)*32 + kqs;     // + slot*8192 + nf*512

  const int nk = klen >> 6;   // BK=64 tiles

#define STAGE_A(koff, s) do { \
    GLOAD16(gA0 + (size_t)(koff), lds + (s)*8192 + la0); \
    GLOAD16(gA1 + (size_t)(koff), lds + (s)*8192 + la1); } while(0)
#define STAGE_B(koff, s) do { \
    GLOAD16(gB0 + (size_t)(koff), lds + 40960 + (s)*8192 + la0); \
    GLOAD16(gB1 + (size_t)(koff), lds + 40960 + (s)*8192 + la1); } while(0)

  // prologue: halves 0,1 (tile 0) + half 2 (tile 1 kk0): 12 loads/thread
  STAGE_A(0, 0); STAGE_B(0, 0);
  STAGE_A(32, 1); STAGE_B(32, 1);
  STAGE_A(64, 2); STAGE_B(64, 2);
  asm volatile("s_waitcnt vmcnt(4)" ::: "memory");   // halves 0,1 landed
  BARRIER();

  int s0 = 0;  // slot of half 2t (advances +2 mod 5)
  for (int t = 0; t < nk; ++t) {
    const int s1  = (s0 + 1 >= 5) ? s0 - 4 : s0 + 1;   // half 2t+1
    const int sp3 = (s0 + 3 >= 5) ? s0 - 2 : s0 + 3;   // half 2t+3
    const int sp4 = (s0 + 4 >= 5) ? s0 - 1 : s0 + 4;   // half 2t+4
    const size_t kOdd = (size_t)(t + 1)*64 + 32;       // half 2t+3 k-offset
    const size_t kEv  = (size_t)(t + 2)*64;            // half 2t+4 k-offset
    const unsigned short* sA0 = lds + s0*8192;
    const unsigned short* sA1 = lds + s1*8192;
    short8 rB0[4], rA0lo[4], rA0hi[4], rB1[4], rA1lo[4], rA1hi[4];

    // ---- P1: issue rB0+rA0lo (8) | rA0hi (4); stage A(2t+3); MFMA Q1 ----
    #pragma unroll
    for (int nf = 0; nf < 4; ++nf) rB0[nf] = *(const short8*)(sA0 + bBase + nf*512);
    #pragma unroll
    for (int mf = 0; mf < 4; ++mf) rA0lo[mf] = *(const short8*)(sA0 + aBase + mf*512);
    SCHEDB();
    #pragma unroll
    for (int mf = 0; mf < 4; ++mf) rA0hi[mf] = *(const short8*)(sA0 + aBase + (mf+4)*512);
    if (t + 1 < nk) STAGE_A(kOdd, sp3);
    SCHEDB();
    asm volatile("s_waitcnt lgkmcnt(4)" ::: "memory");  // rB0,rA0lo ready; rA0hi flying
    SCHEDB();
    __builtin_amdgcn_s_setprio(1);
    #pragma unroll
    for (int mf = 0; mf < 4; ++mf)
      #pragma unroll
      for (int nf = 0; nf < 4; ++nf)
        acc[mf][nf] = __builtin_amdgcn_mfma_f32_16x16x32_bf16(rA0lo[mf], rB0[nf], acc[mf][nf], 0, 0, 0);
    __builtin_amdgcn_s_setprio(0);
    SCHEDB();

    // ---- P2: issue rB1+rA1lo (8); stage B(2t+3); MFMA Q2 (no barrier: mod-5 WAR-safe) ----
    #pragma unroll
    for (int nf = 0; nf < 4; ++nf) rB1[nf] = *(const short8*)(sA1 + bBase + nf*512);
    #pragma unroll
    for (int mf = 0; mf < 4; ++mf) rA1lo[mf] = *(const short8*)(sA1 + aBase + mf*512);
    if (t + 1 < nk) STAGE_B(kOdd, sp3);
    SCHEDB();
    asm volatile("s_waitcnt lgkmcnt(8)" ::: "memory");  // rA0hi ready
    SCHEDB();
    __builtin_amdgcn_s_setprio(1);
    #pragma unroll
    for (int mf = 0; mf < 4; ++mf)
      #pragma unroll
      for (int nf = 0; nf < 4; ++nf)
        acc[mf+4][nf] = __builtin_amdgcn_mfma_f32_16x16x32_bf16(rA0hi[mf], rB0[nf], acc[mf+4][nf], 0, 0, 0);
    __builtin_amdgcn_s_setprio(0);
    SCHEDB();

    // ---- P3: issue rA1hi (4); stage A(2t+4); MFMA Q3 ----
    #pragma unroll
    for (int mf = 0; mf < 4; ++mf) rA1hi[mf] = *(const short8*)(sA1 + aBase + (mf+4)*512);
    if (t + 2 < nk) STAGE_A(kEv, sp4);
    SCHEDB();
    asm volatile("s_waitcnt lgkmcnt(4)" ::: "memory");  // rB1,rA1lo ready; rA1hi flying
    SCHEDB();
    __builtin_amdgcn_s_setprio(1);
    #pragma unroll
    for (int mf = 0; mf < 4; ++mf)
      #pragma unroll
      for (int nf = 0; nf < 4; ++nf)
        acc[mf][nf] = __builtin_amdgcn_mfma_f32_16x16x32_bf16(rA1lo[mf], rB1[nf], acc[mf][nf], 0, 0, 0);
    __builtin_amdgcn_s_setprio(0);
    SCHEDB();

    // ---- P4: stage B(2t+4); MFMA Q4; publish boundary ----
    if (t + 2 < nk) STAGE_B(kEv, sp4);
    SCHEDB();
    asm volatile("s_waitcnt lgkmcnt(0)" ::: "memory");  // rA1hi ready
    SCHEDB();
    __builtin_amdgcn_s_setprio(1);
    #pragma unroll
    for (int mf = 0; mf < 4; ++mf)
      #pragma unroll
      for (int nf = 0; nf < 4; ++nf)
        acc[mf+4][nf] = __builtin_amdgcn_mfma_f32_16x16x32_bf16(rA1hi[mf], rB1[nf], acc[mf+4][nf], 0, 0, 0);
    __builtin_amdgcn_s_setprio(0);
    SCHEDB();

    if (t + 1 < nk) {
      if (t + 2 < nk) asm volatile("s_waitcnt vmcnt(4)" ::: "memory");
      else            asm volatile("s_waitcnt vmcnt(0)" ::: "memory");
      BARRIER();   // tile t+1 (halves 2t+2, 2t+3) published
    }
    s0 += 2; if (s0 >= 5) s0 -= 5;
  }
#undef STAGE_A
#undef STAGE_B

  // epilogue: C/D layout col = lane&15, row = (lane>>4)*4 + reg
  const int col = lane & 15, rbase = (lane >> 4) * 4;
  #pragma unroll
  for (int mf = 0; mf < 8; ++mf) {
    const int gr0 = m0 + wr*128 + mf*16 + rbase;
    #pragma unroll
    for (int nf = 0; nf < 4; ++nf) {
      const int gc = n0 + wc*64 + nf*16 + col;
      const float bv = be ? be[gc] : 0.f;
      #pragma unroll
      for (int r = 0; r < 4; ++r) {
        float v = acc[mf][nf][r] + bv;
        if (RELU) v = fmaxf(v, 0.f);
        Oe[(size_t)(gr0 + r)*N + gc] = f2bf(v);
      }
    }
  }
}

// ---------------- Combine ----------------
__global__ void combine_kernel(const unsigned short* __restrict__ Y0,
                               const unsigned short* __restrict__ Y1,
                               const float* __restrict__ b2c,
                               const int* __restrict__ topk_e, const float* __restrict__ topk_p,
                               const int* __restrict__ pos_arr, float* __restrict__ out)
{
  int token = (int)((blockIdx.x * blockDim.x + threadIdx.x) >> 6);
  int lane = threadIdx.x & 63;
  if (token >= NTOK) return;
  int b = token / T_, t = token - b*T_;
  int s0 = b*S_ + t*2;
  float acc[16];
  #pragma unroll
  for (int i = 0; i < 16; ++i) acc[i] = 0.f;
  #pragma unroll
  for (int k = 0; k < 2; ++k) {
    int pos = pos_arr[s0 + k];
    if (pos < 0) continue;
    int e = topk_e[s0 + k];
    float p = topk_p[s0 + k];
    size_t rowoff = (((size_t)e*B_ + b)*CAP_ + pos) * C_;
    const unsigned short* yr0 = Y0 + rowoff;
    const unsigned short* yr1 = Y1 ? (Y1 + rowoff) : nullptr;
    const float* bb = b2c ? (b2c + (size_t)e * C_) : nullptr;
    #pragma unroll
    for (int i = 0; i < 4; ++i) {
      ushort4 v = ((const ushort4*)yr0)[i*64 + lane];
      float s0v = bf2f(v.x), s1v = bf2f(v.y), s2v = bf2f(v.z), s3v = bf2f(v.w);
      if (yr1) {
        ushort4 u = ((const ushort4*)yr1)[i*64 + lane];
        s0v += bf2f(u.x); s1v += bf2f(u.y); s2v += bf2f(u.z); s3v += bf2f(u.w);
      }
      if (bb) {
        float4 bv = ((const float4*)bb)[i*64 + lane];
        s0v += bv.x; s1v += bv.y; s2v += bv.z; s3v += bv.w;
      }
      acc[i*4+0] += p * s0v;
      acc[i*4+1] += p * s1v;
      acc[i*4+2] += p * s2v;
      acc[i*4+3] += p * s3v;
    }
  }
  float4* orow = (float4*)(out + (size_t)token * C_);
  #pragma unroll
  for (int i = 0; i < 4; ++i) {
    float4 o;
    o.x = acc[i*4+0]; o.y = acc[i*4+1]; o.z = acc[i*4+2]; o.w = acc[i*4+3];
    orow[i*64 + lane] = o;
  }
}

extern "C" void kernel_launch(void* const* d_in, const int* in_sizes, int n_in,
                              void* d_out, int out_size, void* d_ws, size_t ws_size,
                              hipStream_t stream)
{
  const float* x  = (const float*)d_in[0];
  const float* Wg = (const float*)d_in[1];
  const float* bg = (const float*)d_in[2];
  const float* W1 = (const float*)d_in[3];
  const float* b1 = (const float*)d_in[4];
  const float* W2 = (const float*)d_in[5];
  const float* b2 = (const float*)d_in[6];
  float* out = (float*)d_out;

  char* ws = (char*)d_ws;
  size_t off = 0;
  auto alloc = [&](size_t bytes) -> char* {
    char* p = ws + off;
    off = (off + bytes + 255) & ~(size_t)255;
    return p;
  };
  int*   topk_e  = (int*)  alloc((size_t)NTOK * K_ * 4);
  float* topk_p  = (float*)alloc((size_t)NTOK * K_ * 4);
  int*   pos_arr = (int*)  alloc((size_t)B_ * S_ * 4);
  int*   slot_src= (int*)  alloc((size_t)E_ * B_ * CAP_ * 4);
  int*   counts  = (int*)  alloc((size_t)E_ * B_ * 4);
  unsigned short* Ybuf = (unsigned short*)alloc((size_t)E_ * ROWS_PER_E * C_ * 2);
  size_t fixed = off;
  const size_t perE = (size_t)C_ * DFF_ * 2
                    + (size_t)ROWS_PER_E * C_ * 2
                    + (size_t)ROWS_PER_E * DFF_ * 2
                    + 3 * 256;
  int k = 8;
  while (k > 1 && fixed + (size_t)k * perE > ws_size) k >>= 1;
  unsigned short* Wt = (unsigned short*)alloc((size_t)k * C_ * DFF_ * 2);
  unsigned short* Xd = (unsigned short*)alloc((size_t)k * ROWS_PER_E * C_ * 2);
  unsigned short* Hb = (unsigned short*)alloc((size_t)k * ROWS_PER_E * DFF_ * 2);

  router_kernel<<<NTOK/4, 256, 0, stream>>>(x, Wg, bg, topk_e, topk_p);
  scan_kernel<<<B_, 256, 0, stream>>>(topk_e, pos_arr, slot_src, counts);

  const bool splitK2 = (k == 8);

  for (int eb = 0; eb < E_; eb += k) {
    transpose_conv_kernel<<<dim3(DFF_/32, C_/64, k), 256, 0, stream>>>(
        W1 + (size_t)eb * C_ * DFF_, Wt, C_, DFF_);
    dispatch_kernel<<<(k * ROWS_PER_E) / 4, 256, 0, stream>>>(x, slot_src, counts, Xd, eb, k);
    // H = relu(Xd @ W1 + b1)
    {
      int tiles = k * (ROWS_PER_E/256) * (DFF_/256);
      gemm256_kernel<1><<<tiles, 512, 0, stream>>>(
          Xd, Wt, b1 + (size_t)eb * DFF_, Hb, Hb, ROWS_PER_E, DFF_, C_, C_, tiles, tiles);
    }
    transpose_conv_kernel<<<dim3(C_/32, DFF_/64, k), 256, 0, stream>>>(
        W2 + (size_t)eb * DFF_ * C_, Wt, DFF_, C_);
    // Y = H @ W2
    {
      int tiles = k * (ROWS_PER_E/256) * (C_/256);
      if (splitK2) {
        gemm256_kernel<0><<<2*tiles, 512, 0, stream>>>(
            Hb, Wt, nullptr, Ybuf, Xd, ROWS_PER_E, C_, DFF_, DFF_/2, tiles, 2*tiles);
      } else {
        gemm256_kernel<0><<<tiles, 512, 0, stream>>>(
            Hb, Wt, b2 + (size_t)eb * C_, Ybuf + (size_t)eb * ROWS_PER_E * C_,
            Ybuf + (size_t)eb * ROWS_PER_E * C_, ROWS_PER_E, C_, DFF_, DFF_, tiles, tiles);
      }
    }
  }

  combine_kernel<<<NTOK/4, 256, 0, stream>>>(
      Ybuf, splitK2 ? Xd : nullptr, splitK2 ? b2 : nullptr,
      topk_e, topk_p, pos_arr, out);
}